// Round 1
// 1540.329 us; speedup vs baseline: 1.3357x; 1.3357x over previous
//
#include <hip/hip_runtime.h>
#include <math.h>

#define NPKG   20000
#define NTGT   30000
#define NEDGE  100000
#define NTYPES 6
#define INDIM  400
#define KP_IN  416      // INDIM padded to mult of 32
#define MP_PKG 20096    // 157*128
#define MP_TGT 30080    // 235*128

#define LSTR   ((size_t)MP_PKG * 256)   // l_bf per-type stride (elems)
#define RSTR   ((size_t)MP_TGT * 256)   // r_bf / h_t per-type stride
#define XSTR   ((size_t)MP_TGT * KP_IN) // x_t_bf per-type stride
#define LOGSTR ((size_t)MP_TGT * 128)   // logits per-slot stride (f32)
#define SSTR   ((size_t)MP_TGT * 128)   // S per-slot stride (bf16)
#define WSTR   ((size_t)256 * KP_IN)    // weight slot stride

typedef unsigned short ushortT;
typedef unsigned int uintT;
typedef __attribute__((ext_vector_type(8))) short bf16x8;
typedef __attribute__((ext_vector_type(4))) float f32x4;

__device__ __forceinline__ float lrelu(float x) { return x > 0.f ? x : 0.2f * x; }
__device__ __forceinline__ float b2f(ushortT u) {
  union { unsigned int i; float f; } x; x.i = ((unsigned int)u) << 16; return x.f;
}
__device__ __forceinline__ ushortT f2b(float f) {
  unsigned int u = __float_as_uint(f);
  unsigned int r = (u + 0x7FFFu + ((u >> 16) & 1u)) >> 16;
  return (ushortT)r;
}

#define GLL16(g, l)                                                            \
  __builtin_amdgcn_global_load_lds(                                            \
      (const __attribute__((address_space(1))) void*)(g),                      \
      (__attribute__((address_space(3))) void*)(l), 16, 0, 0)

// ---------------- utility ----------------
__global__ void zero_f32(float* __restrict__ p, long n) {
  long i = blockIdx.x * 256 + threadIdx.x, st = (long)gridDim.x * 256;
  for (; i < n; i += st) p[i] = 0.f;
}

// zero pad rows [30000,30080) of S (128 cols) and h_t (256 cols), per type
__global__ void zero_tails(ushortT* __restrict__ S_all, ushortT* __restrict__ h_t) {
  int t = blockIdx.y;
  int i = blockIdx.x * 256 + threadIdx.x;  // 0..7679, each handles 4 elems
  ushort4 z = {0, 0, 0, 0};
  if (i < 2560) {                          // 80*128/4 -> S
    int r = i >> 5, c = (i & 31) * 4;
    *(ushort4*)(S_all + (size_t)t * SSTR + (size_t)(30000 + r) * 128 + c) = z;
  } else if (i < 7680) {                   // 80*256/4 -> h_t
    int k = i - 2560;
    int r = k >> 6, c = (k & 63) * 4;
    *(ushort4*)(h_t + (size_t)t * RSTR + (size_t)(30000 + r) * 256 + c) = z;
  }
}

// f32 [M,K] -> bf16 [*, Kp]; batched over blockIdx.y via strides
__global__ void convert_pad(const float* __restrict__ src, ushortT* __restrict__ dst,
                            int M, int K, int Kp, long srcStride, long dstStride) {
  long z = blockIdx.y;
  const float* s = src + z * srcStride;
  ushortT* d = dst + z * dstStride;
  int idx = blockIdx.x * 256 + threadIdx.x;
  int q = Kp >> 2;
  int row = idx / q, c4 = (idx - row * q) * 4;
  if (row >= M) return;
  float4 v = make_float4(0.f, 0.f, 0.f, 0.f);
  if (c4 < K) v = *(const float4*)(s + (size_t)row * K + c4);  // K mult of 4
  ushort4 o;
  o.x = f2b(v.x); o.y = f2b(v.y); o.z = f2b(v.z); o.w = f2b(v.w);
  *(ushort4*)(d + (size_t)row * Kp + c4) = o;
}

// 13-way batched weight transpose: slots 0..5 = W1s[t], 6 = Wpkg, 7..12 = W1t[t]
__global__ void wtrans13(const float* __restrict__ W1s, const float* __restrict__ Wpkg,
                         const float* __restrict__ W1t, ushortT* __restrict__ WT) {
  int z = blockIdx.y;
  const float* Wb = (z < 6) ? (W1s + (size_t)z * INDIM * 256)
                  : (z == 6) ? Wpkg
                  : (W1t + (size_t)(z - 7) * INDIM * 256);
  ushortT* WTb = WT + (size_t)z * WSTR;
  int idx = blockIdx.x * 256 + threadIdx.x;
  if (idx >= 256 * KP_IN) return;
  int n = idx / KP_IN, k = idx - n * KP_IN;
  WTb[idx] = (k < INDIM) ? f2b(Wb[(size_t)k * 256 + n]) : (ushortT)0;
}

// Wassign [7][256][128] -> [7][128][256] bf16
__global__ void wtransAss(const float* __restrict__ W, ushortT* __restrict__ WT) {
  int z = blockIdx.y;
  const float* Wb = W + (size_t)z * 256 * 128;
  ushortT* WTb = WT + (size_t)z * 128 * 256;
  int idx = blockIdx.x * 256 + threadIdx.x;
  if (idx >= 128 * 256) return;
  int n = idx >> 8, k = idx & 255;
  WTb[idx] = f2b(Wb[(size_t)k * 128 + n]);
}

// ---------------- batched MFMA GEMM ----------------
struct MfmaBatch {
  const ushortT* A[8];
  const ushortT* BT[8];
  void* C[8];
  int M[8];
  int relu[8];
};

template<bool WF32>
__global__ __launch_bounds__(256) void gemm_mfma_b(MfmaBatch d, int Kp, int N) {
  const int z = blockIdx.z;
  const int M = d.M[z];
  const int m0 = blockIdx.y * 128;
  if (m0 >= M) return;
  const ushortT* A = d.A[z];
  const ushortT* BT = d.BT[z];
  const int relu = d.relu[z];
  __shared__ ushortT As[128 * 32];
  __shared__ ushortT Bs[128 * 32];
  const int tid = threadIdx.x;
  const int wave = tid >> 6, lane = tid & 63;
  const int lr = lane & 15, hk = lane >> 4;
  const int am = (wave >> 1) * 64;
  const int bn = (wave & 1) * 64;
  const int n0 = blockIdx.x * 128;

  const int row1 = tid >> 2, cg = (tid & 3) * 8;
  const int row2 = row1 + 64;
  ushortT* ldsA1 = As + ((tid >> 6) << 9);
  ushortT* ldsA2 = As + 2048 + ((tid >> 6) << 9);
  ushortT* ldsB1 = Bs + ((tid >> 6) << 9);
  ushortT* ldsB2 = Bs + 2048 + ((tid >> 6) << 9);
  const ushortT* gA1 = A + (size_t)(m0 + row1) * Kp + cg;
  const ushortT* gA2 = A + (size_t)(m0 + row2) * Kp + cg;
  const ushortT* gB1 = BT + (size_t)(n0 + row1) * Kp + cg;
  const ushortT* gB2 = BT + (size_t)(n0 + row2) * Kp + cg;

  f32x4 acc[4][4];
#pragma unroll
  for (int i = 0; i < 4; ++i)
#pragma unroll
    for (int j = 0; j < 4; ++j) acc[i][j] = (f32x4)(0.f);

  const int nk = Kp >> 5;
  for (int kt = 0; kt < nk; ++kt) {
    const int k0 = kt << 5;
    GLL16(gA1 + k0, ldsA1);
    GLL16(gA2 + k0, ldsA2);
    GLL16(gB1 + k0, ldsB1);
    GLL16(gB2 + k0, ldsB2);
    __syncthreads();
    bf16x8 af[4], bfr[4];
#pragma unroll
    for (int i = 0; i < 4; ++i)
      af[i] = *(const bf16x8*)(As + (size_t)(am + i * 16 + lr) * 32 + hk * 8);
#pragma unroll
    for (int j = 0; j < 4; ++j)
      bfr[j] = *(const bf16x8*)(Bs + (size_t)(bn + j * 16 + lr) * 32 + hk * 8);
#pragma unroll
    for (int i = 0; i < 4; ++i)
#pragma unroll
      for (int j = 0; j < 4; ++j)
        acc[i][j] = __builtin_amdgcn_mfma_f32_16x16x32_bf16(af[i], bfr[j], acc[i][j], 0, 0, 0);
    __syncthreads();
  }

#pragma unroll
  for (int i = 0; i < 4; ++i) {
#pragma unroll
    for (int reg = 0; reg < 4; ++reg) {
      int row = m0 + am + i * 16 + hk * 4 + reg;
      if (row < M) {
#pragma unroll
        for (int j = 0; j < 4; ++j) {
          int col = n0 + bn + j * 16 + lr;
          float v = acc[i][j][reg];
          if (relu) v = fmaxf(v, 0.f);
          if (WF32) ((float*)d.C[z])[(size_t)row * N + col] = v;
          else      ((ushortT*)d.C[z])[(size_t)row * N + col] = f2b(v);
        }
      }
    }
  }
}

// ---------------- batched TN GEMM via MFMA (C = A^T B, split-K atomic) ----------------
// A: [N,128] bf16 (optionally row-gathered via rA). B: [N,K2] bf16 (opt. rB).
// C: [128,K2] f32, accumulated with atomicAdd. One block = 128x128 output
// quadrant (grid.x selects K2-half when K2==256) over a chunk of N.
// LDS layout (per operand, 128 x 32 k-tile, transposed + XOR-swizzled):
//   element (m,k) at ushort index (m>>4)*512 + (k>>3)*128 + ((m&15)^(m>>4))*8 + (k&7)
// -> fragment reads are contiguous-1KB-per-wave (conflict-free), staging
//    writes are b32 with <=2-way conflicts (free per m136).
struct TnBatch {
  const ushortT* A[8];
  const ushortT* B[8];
  float* C[8];
  const int* rA[8];
  const int* rB[8];
  int N[8];
};

template<int K2>
__global__ __launch_bounds__(256) void gemm_tn_mfma(TnBatch d, int chunk, int nchunk) {
  const int mat = blockIdx.z / nchunk;
  const int ci = blockIdx.z - mat * nchunk;
  const int N = d.N[mat];
  const int kbeg = ci * chunk;
  if (kbeg >= N) return;
  const int kend = min(N, kbeg + chunk);
  const ushortT* __restrict__ A = d.A[mat];
  const ushortT* __restrict__ B = d.B[mat];
  const int* __restrict__ rA = d.rA[mat];
  const int* __restrict__ rB = d.rB[mat];
  float* __restrict__ C = d.C[mat];
  const int n0 = (K2 == 256) ? blockIdx.x * 128 : 0;

  __shared__ uintT AtU[2048];
  __shared__ uintT BtU[2048];
  const ushortT* At = (const ushortT*)AtU;
  const ushortT* Bt = (const ushortT*)BtU;

  const int tid = threadIdx.x;
  // staging coords: thread -> (k-pair kp, 16B row-chunk mo8)
  const int kp = tid >> 4;          // 0..15
  const int mo8 = tid & 15;         // 0..15
  const int mh = mo8 >> 1;          // = m>>4 of staged elems
  const int mlo = (mo8 & 1) * 8;    // m&15 base
  const uintT wbase = (uintT)mh * 256 + (uintT)(kp >> 2) * 64 + (uintT)(kp & 3);
  // mfma coords
  const int wave = tid >> 6, lane = tid & 63;
  const int lr = lane & 15, hk = lane >> 4;
  const int wm = wave >> 1, wn = wave & 1;
  int offA[4], offB[4];
#pragma unroll
  for (int i = 0; i < 4; ++i) {
    int Rm = wm * 4 + i, Rn = wn * 4 + i;
    offA[i] = Rm * 512 + hk * 128 + (lr ^ Rm) * 8;
    offB[i] = Rn * 512 + hk * 128 + (lr ^ Rn) * 8;
  }

  f32x4 acc[4][4];
#pragma unroll
  for (int i = 0; i < 4; ++i)
#pragma unroll
    for (int j = 0; j < 4; ++j) acc[i][j] = (f32x4)(0.f);

  for (int k0 = kbeg; k0 < kend; k0 += 32) {
    const int r0 = k0 + kp * 2;
    int ia0, ia1, ib0, ib1;
    if (rA) { int2 v = *(const int2*)(rA + r0); ia0 = v.x; ia1 = v.y; }
    else    { ia0 = r0; ia1 = r0 + 1; }
    if (rB) { int2 v = *(const int2*)(rB + r0); ib0 = v.x; ib1 = v.y; }
    else    { ib0 = r0; ib1 = r0 + 1; }
    bf16x8 a0 = *(const bf16x8*)(A + (size_t)ia0 * 128 + mo8 * 8);
    bf16x8 a1 = *(const bf16x8*)(A + (size_t)ia1 * 128 + mo8 * 8);
    bf16x8 b0, b1;
    if (K2 == 256) {
      b0 = *(const bf16x8*)(B + (size_t)ib0 * 256 + n0 + mo8 * 8);
      b1 = *(const bf16x8*)(B + (size_t)ib1 * 256 + n0 + mo8 * 8);
    } else {
      b0 = *(const bf16x8*)(B + (size_t)ib0 * 128 + mo8 * 8);
      b1 = *(const bf16x8*)(B + (size_t)ib1 * 128 + mo8 * 8);
    }
#pragma unroll
    for (int j = 0; j < 8; ++j) {
      uintT off = wbase + (uintT)((mlo + j) ^ mh) * 4;
      AtU[off] = (uintT)(ushortT)a0[j] | ((uintT)(ushortT)a1[j] << 16);
      BtU[off] = (uintT)(ushortT)b0[j] | ((uintT)(ushortT)b1[j] << 16);
    }
    __syncthreads();
    bf16x8 af[4], bfr[4];
#pragma unroll
    for (int i = 0; i < 4; ++i) af[i] = *(const bf16x8*)(At + offA[i]);
#pragma unroll
    for (int j = 0; j < 4; ++j) bfr[j] = *(const bf16x8*)(Bt + offB[j]);
#pragma unroll
    for (int i = 0; i < 4; ++i)
#pragma unroll
      for (int j = 0; j < 4; ++j)
        acc[i][j] = __builtin_amdgcn_mfma_f32_16x16x32_bf16(af[i], bfr[j], acc[i][j], 0, 0, 0);
    __syncthreads();
  }

#pragma unroll
  for (int i = 0; i < 4; ++i) {
    int mbase = wm * 64 + i * 16 + hk * 4;
#pragma unroll
    for (int reg = 0; reg < 4; ++reg) {
#pragma unroll
      for (int j = 0; j < 4; ++j) {
        int n = n0 + wn * 64 + j * 16 + lr;
        atomicAdd(&C[(size_t)(mbase + reg) * K2 + n], acc[i][j][reg]);
      }
    }
  }
}

// ---------------- CSR build ----------------
__global__ void hist_kernel(const int* __restrict__ tgt, int* __restrict__ counts,
                            int nE, int ntgt) {
  int t = blockIdx.y;
  int e = blockIdx.x * 256 + threadIdx.x;
  if (e < nE) atomicAdd(&counts[t * ntgt + tgt[(long)t * nE + e]], 1);
}

__global__ __launch_bounds__(1024) void scan_kernel(const int* __restrict__ counts_all,
                                                    int* __restrict__ offs_all,
                                                    int* __restrict__ cursor_all, int n) {
  __shared__ int lsum[1024];
  int ty = blockIdx.x;
  const int* counts = counts_all + (long)ty * n;
  int* offs = offs_all + (long)ty * (n + 1);
  int* cursor = cursor_all + (long)ty * n;
  int t = threadIdx.x;
  int chunk = (n + 1023) >> 10;
  int base = t * chunk;
  int s = 0;
  for (int i = 0; i < chunk; ++i) {
    int idx = base + i;
    if (idx < n) s += counts[idx];
  }
  lsum[t] = s;
  __syncthreads();
  for (int off = 1; off < 1024; off <<= 1) {
    int v = (t >= off) ? lsum[t - off] : 0;
    __syncthreads();
    lsum[t] += v;
    __syncthreads();
  }
  int run = lsum[t] - s;
  for (int i = 0; i < chunk; ++i) {
    int idx = base + i;
    if (idx < n) {
      offs[idx] = run;
      cursor[idx] = run;
      run += counts[idx];
    }
  }
  if (t == 1023) offs[n] = lsum[1023];
}

__global__ void scatter_kernel(const int* __restrict__ tgt, int* __restrict__ cursor,
                               int* __restrict__ eorder, int nE, int ntgt) {
  int t = blockIdx.y;
  int e = blockIdx.x * 256 + threadIdx.x;
  if (e < nE) {
    int tv = tgt[(long)t * nE + e];
    int p = atomicAdd(&cursor[t * ntgt + tv], 1);
    eorder[(long)t * nE + p] = e;
  }
}

// ---------------- conv1: fused GATv2 (bf16 in/out), batched over type ----------------
__global__ __launch_bounds__(256) void conv1_agg(const ushortT* __restrict__ l_all,
                                                 const ushortT* __restrict__ r_all,
                                                 const float* __restrict__ a1,
                                                 const int* __restrict__ src_all,
                                                 const int* __restrict__ eorder_all,
                                                 const int* __restrict__ offs_all,
                                                 ushortT* __restrict__ h_all) {
  int t = blockIdx.y;
  const ushortT* l = l_all + (size_t)t * LSTR;
  const ushortT* r = r_all + (size_t)t * RSTR;
  const float* a1t = a1 + t * 256;
  const int* src = src_all + (long)t * NEDGE;
  const int* eorder = eorder_all + (long)t * NEDGE;
  const int* offs = offs_all + (long)t * (NTGT + 1);
  ushortT* hout = h_all + (size_t)t * RSTR;

  int wid = threadIdx.x >> 6, lane = threadIdx.x & 63;
  int v = blockIdx.x * 4 + wid;
  if (v >= NTGT) return;
  ushort4 ru = *(const ushort4*)(r + (size_t)v * 256 + lane * 4);
  float rx = b2f(ru.x), ry = b2f(ru.y), rz = b2f(ru.z), rw = b2f(ru.w);
  const float4 aa = *(const float4*)(a1t + lane * 4);
  int beg = offs[v], end = offs[v + 1];
  float ax = 0.f, ay = 0.f, az = 0.f, aw = 0.f, den = 0.f;
  for (int p = beg; p < end; ++p) {
    int e = eorder[p];
    int u = src[e];
    ushort4 lu = *(const ushort4*)(l + (size_t)u * 256 + lane * 4);
    float lx = b2f(lu.x), ly = b2f(lu.y), lz = b2f(lu.z), lw = b2f(lu.w);
    float s = lrelu(lx + rx) * aa.x + lrelu(ly + ry) * aa.y +
              lrelu(lz + rz) * aa.z + lrelu(lw + rw) * aa.w;
#pragma unroll
    for (int m = 1; m < 16; m <<= 1) s += __shfl_xor(s, m, 64);
    float w = expf(s);
    ax += w * lx; ay += w * ly; az += w * lz; aw += w * lw;
    den += w;
  }
  float inv = (end > beg) ? 1.f / den : 0.f;
  ushort4 o;
  o.x = f2b(fmaxf(ax * inv, 0.f));
  o.y = f2b(fmaxf(ay * inv, 0.f));
  o.z = f2b(fmaxf(az * inv, 0.f));
  o.w = f2b(fmaxf(aw * inv, 0.f));
  *(ushort4*)(hout + (size_t)v * 256 + lane * 4) = o;
}

// ---------------- softmax (f32 logits -> bf16 S) + entropy, batched z=7 ----------------
__global__ __launch_bounds__(256) void softmax_ent(const float* __restrict__ logits_all,
                                                   ushortT* __restrict__ S_all,
                                                   float* __restrict__ ent_slots) {
  int z = blockIdx.y;
  int nrows = (z == 6) ? NPKG : NTGT;
  float inv_n = 1.f / (float)nrows;
  const float* logits = logits_all + (size_t)z * LOGSTR;
  ushortT* Sb = S_all + (size_t)z * SSTR;

  int wid = threadIdx.x >> 6, lane = threadIdx.x & 63;
  int v = blockIdx.x * 4 + wid;
  if (v >= nrows) return;
  const float* row = logits + (size_t)v * 128;
  float x0 = row[lane], x1 = row[lane + 64];
  float m = fmaxf(x0, x1);
#pragma unroll
  for (int sh = 1; sh < 64; sh <<= 1) m = fmaxf(m, __shfl_xor(m, sh, 64));
  float e0 = expf(x0 - m), e1 = expf(x1 - m);
  float s = e0 + e1;
  float t = e0 * (x0 - m) + e1 * (x1 - m);
#pragma unroll
  for (int sh = 1; sh < 64; sh <<= 1) {
    s += __shfl_xor(s, sh, 64);
    t += __shfl_xor(t, sh, 64);
  }
  float inv = 1.f / s;
  Sb[(size_t)v * 128 + lane] = f2b(e0 * inv);
  Sb[(size_t)v * 128 + lane + 64] = f2b(e1 * inv);
  if (lane == 0) {
    float ent = logf(s) - t / s;
    atomicAdd(&ent_slots[blockIdx.x & 255], ent * inv_n);
  }
}

// ---------------- link loss, batched grid(6) ----------------
__global__ __launch_bounds__(256) void link_kernel(const float* __restrict__ Apool_all,
                                                   const float* __restrict__ M_all,
                                                   float Ef, float scale,
                                                   float* __restrict__ loss) {
  __shared__ float red[256];
  int ty = blockIdx.x;
  const float* Apool = Apool_all + (size_t)ty * 16384;
  const float* Mp = M_all + (size_t)6 * 16384;
  const float* Mt = M_all + (size_t)ty * 16384;
  int t = threadIdx.x;
  float s = 0.f;
  for (int i = t; i < 16384; i += 256) s += Mp[i] * Mt[i];
  if (t < 128) s -= 2.f * Apool[t * 129];
  red[t] = s;
  __syncthreads();
  for (int sh = 128; sh > 0; sh >>= 1) {
    if (t < sh) red[t] += red[t + sh];
    __syncthreads();
  }
  if (t == 0) {
    float norm2 = Ef + red[0];
    atomicAdd(loss, sqrtf(fmaxf(norm2, 0.f) + 1e-12f) * scale);
  }
}

// ---------------- conv2 GEMMs, one launch z=12 ----------------
__global__ __launch_bounds__(256) void conv2_gemm(const float* __restrict__ p_buf,
                                                  const float* __restrict__ W2s,
                                                  const float* __restrict__ W2t,
                                                  float* __restrict__ l2r2) {
  const int z = blockIdx.z;
  const int sel = z / 6, t = z - sel * 6;
  const float* A = p_buf + (sel ? (size_t)(t + 1) * 32768 : 0);
  const float* B = (sel ? W2t : W2s) + (size_t)t * 65536;
  float* C = l2r2 + (size_t)sel * 196608 + (size_t)t * 32768;
  const int M = 128, K = 256, N = 256;
  __shared__ __align__(16) float As[16][136];
  __shared__ __align__(16) float Bs[16][136];
  const int tid = threadIdx.x;
  const int tx = tid & 15, ty = tid >> 4;
  const int n0 = blockIdx.x * 128;
  float acc[8][8];
#pragma unroll
  for (int i = 0; i < 8; ++i)
#pragma unroll
    for (int j = 0; j < 8; ++j) acc[i][j] = 0.f;
  for (int k0 = 0; k0 < K; k0 += 16) {
#pragma unroll
    for (int i = 0; i < 8; ++i) {
      int idx = tid + i * 256;
      int rr = idx >> 4, kk = idx & 15;
      As[kk][rr] = (rr < M) ? A[(size_t)rr * K + (k0 + kk)] : 0.f;
    }
#pragma unroll
    for (int i = 0; i < 8; ++i) {
      int idx = tid + i * 256;
      int kk = idx >> 7, nn = idx & 127;
      Bs[kk][nn] = B[(size_t)(k0 + kk) * N + (n0 + nn)];
    }
    __syncthreads();
#pragma unroll
    for (int kk = 0; kk < 16; ++kk) {
      float4 a0 = *(const float4*)&As[kk][ty * 8];
      float4 a1 = *(const float4*)&As[kk][ty * 8 + 4];
      float4 b0 = *(const float4*)&Bs[kk][tx * 8];
      float4 b1 = *(const float4*)&Bs[kk][tx * 8 + 4];
      float av[8] = {a0.x, a0.y, a0.z, a0.w, a1.x, a1.y, a1.z, a1.w};
      float bv[8] = {b0.x, b0.y, b0.z, b0.w, b1.x, b1.y, b1.z, b1.w};
#pragma unroll
      for (int i = 0; i < 8; ++i)
#pragma unroll
        for (int j = 0; j < 8; ++j) acc[i][j] += av[i] * bv[j];
    }
    __syncthreads();
  }
#pragma unroll
  for (int i = 0; i < 8; ++i) {
    int m = ty * 8 + i;
    if (m < M) {
#pragma unroll
      for (int j = 0; j < 8; ++j)
        C[(size_t)m * N + n0 + tx * 8 + j] = acc[i][j];
    }
  }
}

// ---------------- conv2 dense attention ----------------
__global__ __launch_bounds__(256) void conv2_attn(const float* __restrict__ l2_all,
                                                  const float* __restrict__ r2_all,
                                                  const float* __restrict__ Apool_all,
                                                  const float* __restrict__ a2_all,
                                                  float* __restrict__ attn_out) {
  __shared__ float r2row[256], a2s[256], sc[512];
  int j = blockIdx.x;
  int t = blockIdx.y;
  int tid = threadIdx.x;
  const float* l2 = l2_all + (long)t * 32768;
  const float* Apool = Apool_all + (long)t * 16384;
  r2row[tid] = r2_all[(long)t * 32768 + j * 256 + tid];
  a2s[tid] = a2_all[t * 256 + tid];
  __syncthreads();
#pragma unroll
  for (int p = tid; p < 512; p += 256) {
    int i = p >> 2, h = p & 3;
    const float* lr_ = l2 + i * 256 + h * 64;
    const float* rr_ = r2row + h * 64;
    const float* av_ = a2s + h * 64;
    float s = 0.f;
    for (int c = 0; c < 64; ++c) {
      float x = lr_[c] + rr_[c];
      s += (x > 0.f ? x : 0.2f * x) * av_[c];
    }
    sc[p] = (Apool[i * 128 + j] > 0.f) ? s : -1e9f;
  }
  __syncthreads();
  int h = tid >> 6, lane = tid & 63;
  float v0 = sc[lane * 4 + h], v1 = sc[(lane + 64) * 4 + h];
  float m = fmaxf(v0, v1);
#pragma unroll
  for (int sh = 1; sh < 64; sh <<= 1) m = fmaxf(m, __shfl_xor(m, sh, 64));
  float e0 = expf(v0 - m), e1 = expf(v1 - m);
  float s = e0 + e1;
#pragma unroll
  for (int sh = 1; sh < 64; sh <<= 1) s += __shfl_xor(s, sh, 64);
  float inv = 1.f / s;
  attn_out[(long)t * 65536 + (long)lane * 512 + j * 4 + h] = e0 * inv;
  attn_out[(long)t * 65536 + (long)(lane + 64) * 512 + j * 4 + h] = e1 * inv;
}

// ---------------- classifier ----------------
__global__ __launch_bounds__(256) void classifier(const float* __restrict__ p_all,
                                                  const float* __restrict__ Wcls,
                                                  const float* __restrict__ bcls,
                                                  float* __restrict__ out, int nrows) {
  int wid = threadIdx.x >> 6, lane = threadIdx.x & 63;
  int rrow = blockIdx.x * 4 + wid;
  if (rrow >= nrows) return;
  const float4 w = *(const float4*)(Wcls + lane * 4);
  const float4 x = *(const float4*)(p_all + (long)rrow * 256 + lane * 4);
  float s = x.x * w.x + x.y * w.y + x.z * w.z + x.w * w.w;
#pragma unroll
  for (int sh = 1; sh < 64; sh <<= 1) s += __shfl_xor(s, sh, 64);
  if (lane == 0) out[rrow] = 1.f / (1.f + expf(-(s + bcls[0])));
}

__global__ void finalize_loss(const float* __restrict__ red_buf, float* __restrict__ out896) {
  __shared__ float red[256];
  int t = threadIdx.x;
  red[t] = red_buf[t];
  __syncthreads();
  for (int sh = 128; sh > 0; sh >>= 1) {
    if (t < sh) red[t] += red[t + sh];
    __syncthreads();
  }
  if (t == 0) out896[0] = red[0] + red_buf[256];
}

// =====================================================================
extern "C" void kernel_launch(void* const* d_in, const int* in_sizes, int n_in,
                              void* d_out, int out_size, void* d_ws, size_t ws_size,
                              hipStream_t stream) {
  (void)in_sizes; (void)n_in; (void)out_size; (void)ws_size;
  const float* x_pkg  = (const float*)d_in[0];
  const float* x_tgt  = (const float*)d_in[1];
  const int* src_idx  = (const int*)d_in[2];
  const int* tgt_idx  = (const int*)d_in[3];
  const float* W1s    = (const float*)d_in[4];
  const float* W1t    = (const float*)d_in[5];
  const float* a1     = (const float*)d_in[6];
  const float* Wpkg   = (const float*)d_in[7];
  const float* Wassign= (const float*)d_in[8];
  const float* W2s    = (const float*)d_in[9];
  const float* W2t    = (const float*)d_in[10];
  const float* a2     = (const float*)d_in[11];
  const float* Wcls   = (const float*)d_in[12];
  const float* bcls   = (const float*)d_in[13];
  float* out = (float*)d_out;

  char* wp = (char*)d_ws;
  auto alloc = [&](size_t bytes) -> char* {
    char* r = wp;
    wp += (bytes + 255) & ~(size_t)255;
    return r;
  };
  // --- zero region (contiguous): p_buf, M_all, Apool, red_buf, counts ---
  float* p_buf   = (float*)alloc((size_t)7 * 32768 * 4);          // slot0=pkg, 1..6=types
  float* M_all   = (float*)alloc((size_t)7 * 16384 * 4);          // slots 0..5=types, 6=pkg
  float* Apool   = (float*)alloc((size_t)NTYPES * 16384 * 4);
  float* red_buf = (float*)alloc(257 * 4);
  int* counts    = (int*)alloc((size_t)NTYPES * NTGT * 4);
  long zero_n = ((char*)counts + (size_t)NTYPES * NTGT * 4 - (char*)p_buf) / 4;
  // --- rest ---
  int* offs      = (int*)alloc((size_t)NTYPES * (NTGT + 1) * 4);
  int* cursor    = (int*)alloc((size_t)NTYPES * NTGT * 4);
  int* eorder    = (int*)alloc((size_t)NTYPES * NEDGE * 4);
  ushortT* x_pkg_bf = (ushortT*)alloc((size_t)MP_PKG * KP_IN * 2);
  ushortT* x_t_bf   = (ushortT*)alloc((size_t)NTYPES * XSTR * 2);
  ushortT* WT_all   = (ushortT*)alloc((size_t)13 * WSTR * 2);     // 0..5 W1s, 6 Wpkg, 7..12 W1t
  ushortT* WassT    = (ushortT*)alloc((size_t)7 * 128 * 256 * 2); // slot0=pkg, 1..6=types
  ushortT* h_pkg_bf = (ushortT*)alloc((size_t)MP_PKG * 256 * 2);
  ushortT* l_bf     = (ushortT*)alloc((size_t)NTYPES * LSTR * 2);
  ushortT* r_bf     = (ushortT*)alloc((size_t)NTYPES * RSTR * 2);
  ushortT* h_t_bf   = (ushortT*)alloc((size_t)NTYPES * RSTR * 2);
  float* logits     = (float*)alloc((size_t)7 * LOGSTR * 4);      // slots 0..5=types, 6=pkg
  ushortT* S_all    = (ushortT*)alloc((size_t)7 * SSTR * 2);      // slots 0..5=types, 6=pkg
  float* l2r2       = (float*)alloc((size_t)12 * 32768 * 4);      // l2[6], then r2[6]
  float* ent_slots  = red_buf;
  float* loss_acc   = red_buf + 256;
  float* l2_all = l2r2;
  float* r2_all = l2r2 + (size_t)6 * 32768;

  dim3 blk(256);

  // 1. zero all atomic targets in one pass + zero pad rows of S_t / h_t
  zero_f32<<<dim3(512), blk, 0, stream>>>(p_buf, zero_n);
  zero_tails<<<dim3(30, NTYPES), blk, 0, stream>>>(S_all, h_t_bf);

  // 2-3. input conversions
  convert_pad<<<dim3((NPKG * (KP_IN / 4) + 255) / 256, 1), blk, 0, stream>>>(
      x_pkg, x_pkg_bf, NPKG, INDIM, KP_IN, 0, 0);
  convert_pad<<<dim3((NTGT * (KP_IN / 4) + 255) / 256, NTYPES), blk, 0, stream>>>(
      x_tgt, x_t_bf, NTGT, INDIM, KP_IN, (long)NTGT * INDIM, (long)XSTR);

  // 4-5. weight transposes
  wtrans13<<<dim3((256 * KP_IN + 255) / 256, 13), blk, 0, stream>>>(W1s, Wpkg, W1t, WT_all);
  wtransAss<<<dim3((128 * 256 + 255) / 256, 7), blk, 0, stream>>>(Wassign, WassT);

  // 6-8. CSR
  hist_kernel<<<dim3(391, NTYPES), blk, 0, stream>>>(tgt_idx, counts, NEDGE, NTGT);
  scan_kernel<<<dim3(NTYPES), dim3(1024), 0, stream>>>(counts, offs, cursor, NTGT);
  scatter_kernel<<<dim3(391, NTYPES), blk, 0, stream>>>(tgt_idx, cursor, eorder, NEDGE, NTGT);

  // 9. l-gemms (z=0..5) + h_pkg gemm (z=6), all A=x_pkg
  {
    MfmaBatch d{};
    for (int z = 0; z < 6; ++z) {
      d.A[z] = x_pkg_bf; d.BT[z] = WT_all + (size_t)z * WSTR;
      d.C[z] = l_bf + (size_t)z * LSTR; d.M[z] = NPKG; d.relu[z] = 0;
    }
    d.A[6] = x_pkg_bf; d.BT[6] = WT_all + (size_t)6 * WSTR;
    d.C[6] = h_pkg_bf; d.M[6] = NPKG; d.relu[6] = 1;
    d.A[7] = d.A[0]; d.BT[7] = d.BT[0]; d.C[7] = d.C[0]; d.M[7] = 0; d.relu[7] = 0;
    gemm_mfma_b<false><<<dim3(2, 157, 7), blk, 0, stream>>>(d, KP_IN, 256);
  }

  // 10. r-gemms (z=0..5)
  {
    MfmaBatch d{};
    for (int z = 0; z < 6; ++z) {
      d.A[z] = x_t_bf + (size_t)z * XSTR; d.BT[z] = WT_all + (size_t)(7 + z) * WSTR;
      d.C[z] = r_bf + (size_t)z * RSTR; d.M[z] = NTGT; d.relu[z] = 0;
    }
    for (int z = 6; z < 8; ++z) { d.A[z] = d.A[0]; d.BT[z] = d.BT[0]; d.C[z] = d.C[0]; d.M[z] = 0; d.relu[z] = 0; }
    gemm_mfma_b<false><<<dim3(2, 235, 6), blk, 0, stream>>>(d, KP_IN, 256);
  }

  // 11. conv1 (all types)
  conv1_agg<<<dim3(7500, NTYPES), blk, 0, stream>>>(l_bf, r_bf, a1, src_idx, eorder, offs, h_t_bf);

  // 12. assignment logits (z=0..5 types, z=6 pkg)
  {
    MfmaBatch d{};
    for (int z = 0; z < 6; ++z) {
      d.A[z] = h_t_bf + (size_t)z * RSTR; d.BT[z] = WassT + (size_t)(z + 1) * 128 * 256;
      d.C[z] = logits + (size_t)z * LOGSTR; d.M[z] = NTGT; d.relu[z] = 0;
    }
    d.A[6] = h_pkg_bf; d.BT[6] = WassT; d.C[6] = logits + (size_t)6 * LOGSTR;
    d.M[6] = NPKG; d.relu[6] = 0;
    d.A[7] = d.A[0]; d.BT[7] = d.BT[0]; d.C[7] = d.C[0]; d.M[7] = 0; d.relu[7] = 0;
    gemm_mfma_b<true><<<dim3(1, 235, 7), blk, 0, stream>>>(d, 256, 128);
  }

  // 13. softmax + entropy (z=0..6)
  softmax_ent<<<dim3(7500, 7), blk, 0, stream>>>(logits, S_all, ent_slots);

  // 14. pooled features P = S^T h (mats 0..5 types, 6 pkg) — MFMA TN
  {
    TnBatch d{};
    for (int m = 0; m < 6; ++m) {
      d.A[m] = S_all + (size_t)m * SSTR; d.B[m] = h_t_bf + (size_t)m * RSTR;
      d.C[m] = p_buf + (size_t)(m + 1) * 32768;
      d.rA[m] = nullptr; d.rB[m] = nullptr; d.N[m] = MP_TGT;  // pad rows are zeroed
    }
    d.A[6] = S_all + (size_t)6 * SSTR; d.B[6] = h_pkg_bf; d.C[6] = p_buf;
    d.rA[6] = nullptr; d.rB[6] = nullptr; d.N[6] = NPKG;
    d.A[7] = d.A[0]; d.B[7] = d.B[0]; d.C[7] = d.C[0]; d.rA[7] = nullptr; d.rB[7] = nullptr; d.N[7] = 0;
    gemm_tn_mfma<256><<<dim3(2, 1, 7 * 30), blk, 0, stream>>>(d, 1024, 30);
  }

  // 15. M = S^T S (mats 0..5 types, 6 pkg) — MFMA TN
  {
    TnBatch d{};
    for (int m = 0; m < 7; ++m) {
      const ushortT* S = S_all + (size_t)m * SSTR;
      d.A[m] = S; d.B[m] = S; d.C[m] = M_all + (size_t)m * 16384;
      d.rA[m] = nullptr; d.rB[m] = nullptr; d.N[m] = (m == 6) ? NPKG : MP_TGT;
    }
    d.A[7] = d.A[0]; d.B[7] = d.B[0]; d.C[7] = d.C[0]; d.rA[7] = nullptr; d.rB[7] = nullptr; d.N[7] = 0;
    gemm_tn_mfma<128><<<dim3(1, 1, 7 * 30), blk, 0, stream>>>(d, 1024, 30);
  }

  // 16. Apool = gathered S_pkg^T S_t over edges (mats 0..5) — MFMA TN + gather
  {
    TnBatch d{};
    for (int m = 0; m < 6; ++m) {
      d.A[m] = S_all + (size_t)6 * SSTR; d.B[m] = S_all + (size_t)m * SSTR;
      d.C[m] = Apool + (size_t)m * 16384;
      d.rA[m] = src_idx + (long)m * NEDGE; d.rB[m] = tgt_idx + (long)m * NEDGE;
      d.N[m] = NEDGE;
    }
    for (int m = 6; m < 8; ++m) { d.A[m] = d.A[0]; d.B[m] = d.B[0]; d.C[m] = d.C[0]; d.rA[m] = nullptr; d.rB[m] = nullptr; d.N[m] = 0; }
    gemm_tn_mfma<128><<<dim3(1, 1, 6 * 98), blk, 0, stream>>>(d, 1024, 98);
  }

  // 17. link losses
  link_kernel<<<dim3(6), blk, 0, stream>>>(Apool, M_all, (float)NEDGE,
                                           1.f / ((float)NPKG * (float)NTGT), loss_acc);

  // 18-19. conv2
  conv2_gemm<<<dim3(2, 1, 12), blk, 0, stream>>>(p_buf, W2s, W2t, l2r2);
  conv2_attn<<<dim3(128, NTYPES), blk, 0, stream>>>(l2_all, r2_all, Apool, a2, out + 897);

  // 20-21. classifier + loss
  classifier<<<dim3(224), blk, 0, stream>>>(p_buf, Wcls, bcls, out, 896);
  finalize_loss<<<dim3(1), blk, 0, stream>>>(red_buf, out + 896);
}

// Round 3
// 1274.286 us; speedup vs baseline: 1.6145x; 1.2088x over previous
//
#include <hip/hip_runtime.h>
#include <math.h>

#define NPKG   20000
#define NTGT   30000
#define NEDGE  100000
#define NTYPES 6
#define INDIM  400
#define KP_IN  416      // INDIM padded to mult of 32
#define MP_PKG 20096    // 157*128
#define MP_TGT 30080    // 235*128

#define LSTR   ((size_t)MP_PKG * 256)   // l_bf per-type stride (elems)
#define RSTR   ((size_t)MP_TGT * 256)   // r_bf / h_t per-type stride
#define XSTR   ((size_t)MP_TGT * KP_IN) // x_t_bf per-type stride
#define LOGSTR ((size_t)MP_TGT * 128)   // logits per-slot stride (f32)
#define SSTR   ((size_t)MP_TGT * 128)   // S per-slot stride (bf16)
#define WSTR   ((size_t)256 * KP_IN)    // weight slot stride

typedef unsigned short ushortT;
typedef unsigned int uintT;
typedef __attribute__((ext_vector_type(8))) short bf16x8;
typedef __attribute__((ext_vector_type(8))) short short8b;
typedef __attribute__((ext_vector_type(4))) float f32x4;

__device__ __forceinline__ float lrelu(float x) { return x > 0.f ? x : 0.2f * x; }
__device__ __forceinline__ float b2f(ushortT u) {
  union { unsigned int i; float f; } x; x.i = ((unsigned int)u) << 16; return x.f;
}
__device__ __forceinline__ ushortT f2b(float f) {
  unsigned int u = __float_as_uint(f);
  unsigned int r = (u + 0x7FFFu + ((u >> 16) & 1u)) >> 16;
  return (ushortT)r;
}

#define GLL16(g, l)                                                            \
  __builtin_amdgcn_global_load_lds(                                            \
      (const __attribute__((address_space(1))) void*)(g),                      \
      (__attribute__((address_space(3))) void*)(l), 16, 0, 0)

// ---------------- utility ----------------
__global__ void zero_f32(float* __restrict__ p, long n) {
  long i = blockIdx.x * 256 + threadIdx.x, st = (long)gridDim.x * 256;
  for (; i < n; i += st) p[i] = 0.f;
}

// zero pad rows [30000,30080) of S (128 cols) and h_t (256 cols), per type
__global__ void zero_tails(ushortT* __restrict__ S_all, ushortT* __restrict__ h_t) {
  int t = blockIdx.y;
  int i = blockIdx.x * 256 + threadIdx.x;  // 0..7679, each handles 4 elems
  ushort4 z = {0, 0, 0, 0};
  if (i < 2560) {                          // 80*128/4 -> S
    int r = i >> 5, c = (i & 31) * 4;
    *(ushort4*)(S_all + (size_t)t * SSTR + (size_t)(30000 + r) * 128 + c) = z;
  } else if (i < 7680) {                   // 80*256/4 -> h_t
    int k = i - 2560;
    int r = k >> 6, c = (k & 63) * 4;
    *(ushort4*)(h_t + (size_t)t * RSTR + (size_t)(30000 + r) * 256 + c) = z;
  }
}

// f32 [M,K] -> bf16 [*, Kp]; batched over blockIdx.y via strides
__global__ void convert_pad(const float* __restrict__ src, ushortT* __restrict__ dst,
                            int M, int K, int Kp, long srcStride, long dstStride) {
  long z = blockIdx.y;
  const float* s = src + z * srcStride;
  ushortT* d = dst + z * dstStride;
  int idx = blockIdx.x * 256 + threadIdx.x;
  int q = Kp >> 2;
  int row = idx / q, c4 = (idx - row * q) * 4;
  if (row >= M) return;
  float4 v = make_float4(0.f, 0.f, 0.f, 0.f);
  if (c4 < K) v = *(const float4*)(s + (size_t)row * K + c4);  // K mult of 4
  ushort4 o;
  o.x = f2b(v.x); o.y = f2b(v.y); o.z = f2b(v.z); o.w = f2b(v.w);
  *(ushort4*)(d + (size_t)row * Kp + c4) = o;
}

// 13-way batched weight transpose: slots 0..5 = W1s[t], 6 = Wpkg, 7..12 = W1t[t]
__global__ void wtrans13(const float* __restrict__ W1s, const float* __restrict__ Wpkg,
                         const float* __restrict__ W1t, ushortT* __restrict__ WT) {
  int z = blockIdx.y;
  const float* Wb = (z < 6) ? (W1s + (size_t)z * INDIM * 256)
                  : (z == 6) ? Wpkg
                  : (W1t + (size_t)(z - 7) * INDIM * 256);
  ushortT* WTb = WT + (size_t)z * WSTR;
  int idx = blockIdx.x * 256 + threadIdx.x;
  if (idx >= 256 * KP_IN) return;
  int n = idx / KP_IN, k = idx - n * KP_IN;
  WTb[idx] = (k < INDIM) ? f2b(Wb[(size_t)k * 256 + n]) : (ushortT)0;
}

// Wassign [7][256][128] -> [7][128][256] bf16
__global__ void wtransAss(const float* __restrict__ W, ushortT* __restrict__ WT) {
  int z = blockIdx.y;
  const float* Wb = W + (size_t)z * 256 * 128;
  ushortT* WTb = WT + (size_t)z * 128 * 256;
  int idx = blockIdx.x * 256 + threadIdx.x;
  if (idx >= 128 * 256) return;
  int n = idx >> 8, k = idx & 255;
  WTb[idx] = f2b(Wb[(size_t)k * 128 + n]);
}

// ---------------- batched MFMA GEMM ----------------
struct MfmaBatch {
  const ushortT* A[8];
  const ushortT* BT[8];
  void* C[8];
  int M[8];
  int relu[8];
};

template<bool WF32>
__global__ __launch_bounds__(256) void gemm_mfma_b(MfmaBatch d, int Kp, int N) {
  const int z = blockIdx.z;
  const int M = d.M[z];
  const int m0 = blockIdx.y * 128;
  if (m0 >= M) return;
  const ushortT* A = d.A[z];
  const ushortT* BT = d.BT[z];
  const int relu = d.relu[z];
  __shared__ ushortT As[128 * 32];
  __shared__ ushortT Bs[128 * 32];
  const int tid = threadIdx.x;
  const int wave = tid >> 6, lane = tid & 63;
  const int lr = lane & 15, hk = lane >> 4;
  const int am = (wave >> 1) * 64;
  const int bn = (wave & 1) * 64;
  const int n0 = blockIdx.x * 128;

  const int row1 = tid >> 2, cg = (tid & 3) * 8;
  const int row2 = row1 + 64;
  ushortT* ldsA1 = As + ((tid >> 6) << 9);
  ushortT* ldsA2 = As + 2048 + ((tid >> 6) << 9);
  ushortT* ldsB1 = Bs + ((tid >> 6) << 9);
  ushortT* ldsB2 = Bs + 2048 + ((tid >> 6) << 9);
  const ushortT* gA1 = A + (size_t)(m0 + row1) * Kp + cg;
  const ushortT* gA2 = A + (size_t)(m0 + row2) * Kp + cg;
  const ushortT* gB1 = BT + (size_t)(n0 + row1) * Kp + cg;
  const ushortT* gB2 = BT + (size_t)(n0 + row2) * Kp + cg;

  f32x4 acc[4][4];
#pragma unroll
  for (int i = 0; i < 4; ++i)
#pragma unroll
    for (int j = 0; j < 4; ++j) acc[i][j] = (f32x4)(0.f);

  const int nk = Kp >> 5;
  for (int kt = 0; kt < nk; ++kt) {
    const int k0 = kt << 5;
    GLL16(gA1 + k0, ldsA1);
    GLL16(gA2 + k0, ldsA2);
    GLL16(gB1 + k0, ldsB1);
    GLL16(gB2 + k0, ldsB2);
    __syncthreads();
    bf16x8 af[4], bfr[4];
#pragma unroll
    for (int i = 0; i < 4; ++i)
      af[i] = *(const bf16x8*)(As + (size_t)(am + i * 16 + lr) * 32 + hk * 8);
#pragma unroll
    for (int j = 0; j < 4; ++j)
      bfr[j] = *(const bf16x8*)(Bs + (size_t)(bn + j * 16 + lr) * 32 + hk * 8);
#pragma unroll
    for (int i = 0; i < 4; ++i)
#pragma unroll
      for (int j = 0; j < 4; ++j)
        acc[i][j] = __builtin_amdgcn_mfma_f32_16x16x32_bf16(af[i], bfr[j], acc[i][j], 0, 0, 0);
    __syncthreads();
  }

#pragma unroll
  for (int i = 0; i < 4; ++i) {
#pragma unroll
    for (int reg = 0; reg < 4; ++reg) {
      int row = m0 + am + i * 16 + hk * 4 + reg;
      if (row < M) {
#pragma unroll
        for (int j = 0; j < 4; ++j) {
          int col = n0 + bn + j * 16 + lr;
          float v = acc[i][j][reg];
          if (relu) v = fmaxf(v, 0.f);
          if (WF32) ((float*)d.C[z])[(size_t)row * N + col] = v;
          else      ((ushortT*)d.C[z])[(size_t)row * N + col] = f2b(v);
        }
      }
    }
  }
}

// ---------------- batched TN GEMM via MFMA (C = A^T B, split-K atomic) ----------------
struct TnBatch {
  const ushortT* A[8];
  const ushortT* B[8];
  float* C[8];
  const int* rA[8];
  const int* rB[8];
  int N[8];
};

template<int K2>
__global__ __launch_bounds__(256) void gemm_tn_mfma(TnBatch d, int chunk, int nchunk) {
  const int mat = blockIdx.z / nchunk;
  const int ci = blockIdx.z - mat * nchunk;
  const int N = d.N[mat];
  const int kbeg = ci * chunk;
  if (kbeg >= N) return;
  const int kend = min(N, kbeg + chunk);
  const ushortT* __restrict__ A = d.A[mat];
  const ushortT* __restrict__ B = d.B[mat];
  const int* __restrict__ rA = d.rA[mat];
  const int* __restrict__ rB = d.rB[mat];
  float* __restrict__ C = d.C[mat];
  const int n0 = (K2 == 256) ? blockIdx.x * 128 : 0;

  __shared__ uintT AtU[2048];
  __shared__ uintT BtU[2048];
  const ushortT* At = (const ushortT*)AtU;
  const ushortT* Bt = (const ushortT*)BtU;

  const int tid = threadIdx.x;
  const int kp = tid >> 4;          // 0..15
  const int mo8 = tid & 15;         // 0..15
  const int mh = mo8 >> 1;          // = m>>4 of staged elems
  const int mlo = (mo8 & 1) * 8;    // m&15 base
  const uintT wbase = (uintT)mh * 256 + (uintT)(kp >> 2) * 64 + (uintT)(kp & 3);
  const int wave = tid >> 6, lane = tid & 63;
  const int lr = lane & 15, hk = lane >> 4;
  const int wm = wave >> 1, wn = wave & 1;
  int offA[4], offB[4];
#pragma unroll
  for (int i = 0; i < 4; ++i) {
    int Rm = wm * 4 + i, Rn = wn * 4 + i;
    offA[i] = Rm * 512 + hk * 128 + (lr ^ Rm) * 8;
    offB[i] = Rn * 512 + hk * 128 + (lr ^ Rn) * 8;
  }

  f32x4 acc[4][4];
#pragma unroll
  for (int i = 0; i < 4; ++i)
#pragma unroll
    for (int j = 0; j < 4; ++j) acc[i][j] = (f32x4)(0.f);

  for (int k0 = kbeg; k0 < kend; k0 += 32) {
    const int r0 = k0 + kp * 2;
    int ia0, ia1, ib0, ib1;
    if (rA) { int2 v = *(const int2*)(rA + r0); ia0 = v.x; ia1 = v.y; }
    else    { ia0 = r0; ia1 = r0 + 1; }
    if (rB) { int2 v = *(const int2*)(rB + r0); ib0 = v.x; ib1 = v.y; }
    else    { ib0 = r0; ib1 = r0 + 1; }
    bf16x8 a0 = *(const bf16x8*)(A + (size_t)ia0 * 128 + mo8 * 8);
    bf16x8 a1 = *(const bf16x8*)(A + (size_t)ia1 * 128 + mo8 * 8);
    bf16x8 b0, b1;
    if (K2 == 256) {
      b0 = *(const bf16x8*)(B + (size_t)ib0 * 256 + n0 + mo8 * 8);
      b1 = *(const bf16x8*)(B + (size_t)ib1 * 256 + n0 + mo8 * 8);
    } else {
      b0 = *(const bf16x8*)(B + (size_t)ib0 * 128 + mo8 * 8);
      b1 = *(const bf16x8*)(B + (size_t)ib1 * 128 + mo8 * 8);
    }
#pragma unroll
    for (int j = 0; j < 8; ++j) {
      uintT off = wbase + (uintT)((mlo + j) ^ mh) * 4;
      AtU[off] = (uintT)(ushortT)a0[j] | ((uintT)(ushortT)a1[j] << 16);
      BtU[off] = (uintT)(ushortT)b0[j] | ((uintT)(ushortT)b1[j] << 16);
    }
    __syncthreads();
    bf16x8 af[4], bfr[4];
#pragma unroll
    for (int i = 0; i < 4; ++i) af[i] = *(const bf16x8*)(At + offA[i]);
#pragma unroll
    for (int j = 0; j < 4; ++j) bfr[j] = *(const bf16x8*)(Bt + offB[j]);
#pragma unroll
    for (int i = 0; i < 4; ++i)
#pragma unroll
      for (int j = 0; j < 4; ++j)
        acc[i][j] = __builtin_amdgcn_mfma_f32_16x16x32_bf16(af[i], bfr[j], acc[i][j], 0, 0, 0);
    __syncthreads();
  }

#pragma unroll
  for (int i = 0; i < 4; ++i) {
    int mbase = wm * 64 + i * 16 + hk * 4;
#pragma unroll
    for (int reg = 0; reg < 4; ++reg) {
#pragma unroll
      for (int j = 0; j < 4; ++j) {
        int n = n0 + wn * 64 + j * 16 + lr;
        atomicAdd(&C[(size_t)(mbase + reg) * K2 + n], acc[i][j][reg]);
      }
    }
  }
}

// ---------------- CSR build ----------------
__global__ void hist_kernel(const int* __restrict__ tgt, int* __restrict__ counts,
                            int nE, int ntgt) {
  int t = blockIdx.y;
  int e = blockIdx.x * 256 + threadIdx.x;
  if (e < nE) atomicAdd(&counts[t * ntgt + tgt[(long)t * nE + e]], 1);
}

__global__ __launch_bounds__(1024) void scan_kernel(const int* __restrict__ counts_all,
                                                    int* __restrict__ offs_all,
                                                    int* __restrict__ cursor_all, int n) {
  __shared__ int lsum[1024];
  int ty = blockIdx.x;
  const int* counts = counts_all + (long)ty * n;
  int* offs = offs_all + (long)ty * (n + 1);
  int* cursor = cursor_all + (long)ty * n;
  int t = threadIdx.x;
  int chunk = (n + 1023) >> 10;
  int base = t * chunk;
  int s = 0;
  for (int i = 0; i < chunk; ++i) {
    int idx = base + i;
    if (idx < n) s += counts[idx];
  }
  lsum[t] = s;
  __syncthreads();
  for (int off = 1; off < 1024; off <<= 1) {
    int v = (t >= off) ? lsum[t - off] : 0;
    __syncthreads();
    lsum[t] += v;
    __syncthreads();
  }
  int run = lsum[t] - s;
  for (int i = 0; i < chunk; ++i) {
    int idx = base + i;
    if (idx < n) {
      offs[idx] = run;
      cursor[idx] = run;
      run += counts[idx];
    }
  }
  if (t == 1023) offs[n] = lsum[1023];
}

__global__ void scatter_kernel(const int* __restrict__ tgt, int* __restrict__ cursor,
                               int* __restrict__ eorder, int nE, int ntgt) {
  int t = blockIdx.y;
  int e = blockIdx.x * 256 + threadIdx.x;
  if (e < nE) {
    int tv = tgt[(long)t * nE + e];
    int p = atomicAdd(&cursor[t * ntgt + tv], 1);
    eorder[(long)t * nE + p] = e;
  }
}

// ---------------- conv1: fused GATv2 (bf16 in/out), batched over type ----------------
__global__ __launch_bounds__(256) void conv1_agg(const ushortT* __restrict__ l_all,
                                                 const ushortT* __restrict__ r_all,
                                                 const float* __restrict__ a1,
                                                 const int* __restrict__ src_all,
                                                 const int* __restrict__ eorder_all,
                                                 const int* __restrict__ offs_all,
                                                 ushortT* __restrict__ h_all) {
  int t = blockIdx.y;
  const ushortT* l = l_all + (size_t)t * LSTR;
  const ushortT* r = r_all + (size_t)t * RSTR;
  const float* a1t = a1 + t * 256;
  const int* src = src_all + (long)t * NEDGE;
  const int* eorder = eorder_all + (long)t * NEDGE;
  const int* offs = offs_all + (long)t * (NTGT + 1);
  ushortT* hout = h_all + (size_t)t * RSTR;

  int wid = threadIdx.x >> 6, lane = threadIdx.x & 63;
  int v = blockIdx.x * 4 + wid;
  if (v >= NTGT) return;
  ushort4 ru = *(const ushort4*)(r + (size_t)v * 256 + lane * 4);
  float rx = b2f(ru.x), ry = b2f(ru.y), rz = b2f(ru.z), rw = b2f(ru.w);
  const float4 aa = *(const float4*)(a1t + lane * 4);
  int beg = offs[v], end = offs[v + 1];
  float ax = 0.f, ay = 0.f, az = 0.f, aw = 0.f, den = 0.f;
  for (int p = beg; p < end; ++p) {
    int e = eorder[p];
    int u = src[e];
    ushort4 lu = *(const ushort4*)(l + (size_t)u * 256 + lane * 4);
    float lx = b2f(lu.x), ly = b2f(lu.y), lz = b2f(lu.z), lw = b2f(lu.w);
    float s = lrelu(lx + rx) * aa.x + lrelu(ly + ry) * aa.y +
              lrelu(lz + rz) * aa.z + lrelu(lw + rw) * aa.w;
#pragma unroll
    for (int m = 1; m < 16; m <<= 1) s += __shfl_xor(s, m, 64);
    float w = expf(s);
    ax += w * lx; ay += w * ly; az += w * lz; aw += w * lw;
    den += w;
  }
  float inv = (end > beg) ? 1.f / den : 0.f;
  ushort4 o;
  o.x = f2b(fmaxf(ax * inv, 0.f));
  o.y = f2b(fmaxf(ay * inv, 0.f));
  o.z = f2b(fmaxf(az * inv, 0.f));
  o.w = f2b(fmaxf(aw * inv, 0.f));
  *(ushort4*)(hout + (size_t)v * 256 + lane * 4) = o;
}

// ---------------- softmax (f32 logits -> bf16 S) + entropy, batched z=7 ----------------
// v2: 8 lanes per row, 16 elems/lane. 4 independent float4 loads per thread,
// 3-level shuffle reduces, packed 16-bf16 store. Pad rows masked (loads are
// in-bounds: every slot is MP_TGT-row strided).
__global__ __launch_bounds__(256) void softmax_ent(const float* __restrict__ logits_all,
                                                   ushortT* __restrict__ S_all,
                                                   float* __restrict__ ent_slots) {
  int z = blockIdx.y;
  int nrows = (z == 6) ? NPKG : NTGT;
  if (blockIdx.x * 32 >= nrows) return;
  float inv_n = 1.f / (float)nrows;
  const float* logits = logits_all + (size_t)z * LOGSTR;
  ushortT* Sb = S_all + (size_t)z * SSTR;

  int wid = threadIdx.x >> 6, lane = threadIdx.x & 63;
  int rloc = lane >> 3, seg = lane & 7;
  int v = blockIdx.x * 32 + wid * 8 + rloc;
  bool valid = v < nrows;

  const float* row = logits + (size_t)v * 128 + seg * 16;
  f32x4 x0 = *(const f32x4*)(row);
  f32x4 x1 = *(const f32x4*)(row + 4);
  f32x4 x2 = *(const f32x4*)(row + 8);
  f32x4 x3 = *(const f32x4*)(row + 12);

  float m01 = fmaxf(fmaxf(x0.x, x0.y), fmaxf(x0.z, x0.w));
  float m11 = fmaxf(fmaxf(x1.x, x1.y), fmaxf(x1.z, x1.w));
  float m21 = fmaxf(fmaxf(x2.x, x2.y), fmaxf(x2.z, x2.w));
  float m31 = fmaxf(fmaxf(x3.x, x3.y), fmaxf(x3.z, x3.w));
  float m = fmaxf(fmaxf(m01, m11), fmaxf(m21, m31));
#pragma unroll
  for (int sh = 1; sh < 8; sh <<= 1) m = fmaxf(m, __shfl_xor(m, sh, 64));

  f32x4 e0, e1, e2, e3;
  float s = 0.f, tt = 0.f;
#pragma unroll
  for (int q = 0; q < 4; ++q) {
    f32x4 xq = (q == 0) ? x0 : (q == 1) ? x1 : (q == 2) ? x2 : x3;
    f32x4 eq;
#pragma unroll
    for (int c = 0; c < 4; ++c) {
      float d = xq[c] - m;
      float e = expf(d);
      eq[c] = e;
      s += e;
      tt += e * d;
    }
    if (q == 0) e0 = eq; else if (q == 1) e1 = eq; else if (q == 2) e2 = eq; else e3 = eq;
  }
#pragma unroll
  for (int sh = 1; sh < 8; sh <<= 1) {
    s += __shfl_xor(s, sh, 64);
    tt += __shfl_xor(tt, sh, 64);
  }
  float inv = 1.f / s;

  if (valid) {
    short8b lo, hi;
#pragma unroll
    for (int c = 0; c < 4; ++c) {
      lo[c]     = (short)f2b(e0[c] * inv);
      lo[c + 4] = (short)f2b(e1[c] * inv);
      hi[c]     = (short)f2b(e2[c] * inv);
      hi[c + 4] = (short)f2b(e3[c] * inv);
    }
    ushortT* op = Sb + (size_t)v * 128 + seg * 16;
    *(short8b*)(op) = lo;
    *(short8b*)(op + 8) = hi;
  }

  float val = (valid && seg == 0) ? (logf(s) - tt / s) * inv_n : 0.f;
#pragma unroll
  for (int sh = 1; sh < 64; sh <<= 1) val += __shfl_xor(val, sh, 64);
  if (lane == 0) atomicAdd(&ent_slots[blockIdx.x & 255], val);
}

// ---------------- link loss, batched grid(6) ----------------
__global__ __launch_bounds__(256) void link_kernel(const float* __restrict__ Apool_all,
                                                   const float* __restrict__ M_all,
                                                   float Ef, float scale,
                                                   float* __restrict__ loss) {
  __shared__ float red[256];
  int ty = blockIdx.x;
  const float* Apool = Apool_all + (size_t)ty * 16384;
  const float* Mp = M_all + (size_t)6 * 16384;
  const float* Mt = M_all + (size_t)ty * 16384;
  int t = threadIdx.x;
  float s = 0.f;
  for (int i = t; i < 16384; i += 256) s += Mp[i] * Mt[i];
  if (t < 128) s -= 2.f * Apool[t * 129];
  red[t] = s;
  __syncthreads();
  for (int sh = 128; sh > 0; sh >>= 1) {
    if (t < sh) red[t] += red[t + sh];
    __syncthreads();
  }
  if (t == 0) {
    float norm2 = Ef + red[0];
    atomicAdd(loss, sqrtf(fmaxf(norm2, 0.f) + 1e-12f) * scale);
  }
}

// ---------------- conv2 GEMMs, one launch z=12 ----------------
__global__ __launch_bounds__(256) void conv2_gemm(const float* __restrict__ p_buf,
                                                  const float* __restrict__ W2s,
                                                  const float* __restrict__ W2t,
                                                  float* __restrict__ l2r2) {
  const int z = blockIdx.z;
  const int sel = z / 6, t = z - sel * 6;
  const float* A = p_buf + (sel ? (size_t)(t + 1) * 32768 : 0);
  const float* B = (sel ? W2t : W2s) + (size_t)t * 65536;
  float* C = l2r2 + (size_t)sel * 196608 + (size_t)t * 32768;
  const int M = 128, K = 256, N = 256;
  __shared__ __align__(16) float As[16][136];
  __shared__ __align__(16) float Bs[16][136];
  const int tid = threadIdx.x;
  const int tx = tid & 15, ty = tid >> 4;
  const int n0 = blockIdx.x * 128;
  float acc[8][8];
#pragma unroll
  for (int i = 0; i < 8; ++i)
#pragma unroll
    for (int j = 0; j < 8; ++j) acc[i][j] = 0.f;
  for (int k0 = 0; k0 < K; k0 += 16) {
#pragma unroll
    for (int i = 0; i < 8; ++i) {
      int idx = tid + i * 256;
      int rr = idx >> 4, kk = idx & 15;
      As[kk][rr] = (rr < M) ? A[(size_t)rr * K + (k0 + kk)] : 0.f;
    }
#pragma unroll
    for (int i = 0; i < 8; ++i) {
      int idx = tid + i * 256;
      int kk = idx >> 7, nn = idx & 127;
      Bs[kk][nn] = B[(size_t)(k0 + kk) * N + (n0 + nn)];
    }
    __syncthreads();
#pragma unroll
    for (int kk = 0; kk < 16; ++kk) {
      float4 a0 = *(const float4*)&As[kk][ty * 8];
      float4 a1 = *(const float4*)&As[kk][ty * 8 + 4];
      float4 b0 = *(const float4*)&Bs[kk][tx * 8];
      float4 b1 = *(const float4*)&Bs[kk][tx * 8 + 4];
      float av[8] = {a0.x, a0.y, a0.z, a0.w, a1.x, a1.y, a1.z, a1.w};
      float bv[8] = {b0.x, b0.y, b0.z, b0.w, b1.x, b1.y, b1.z, b1.w};
#pragma unroll
      for (int i = 0; i < 8; ++i)
#pragma unroll
        for (int j = 0; j < 8; ++j) acc[i][j] += av[i] * bv[j];
    }
    __syncthreads();
  }
#pragma unroll
  for (int i = 0; i < 8; ++i) {
    int m = ty * 8 + i;
    if (m < M) {
#pragma unroll
      for (int j = 0; j < 8; ++j)
        C[(size_t)m * N + n0 + tx * 8 + j] = acc[i][j];
    }
  }
}

// ---------------- conv2 dense attention ----------------
__global__ __launch_bounds__(256) void conv2_attn(const float* __restrict__ l2_all,
                                                  const float* __restrict__ r2_all,
                                                  const float* __restrict__ Apool_all,
                                                  const float* __restrict__ a2_all,
                                                  float* __restrict__ attn_out) {
  __shared__ float r2row[256], a2s[256], sc[512];
  int j = blockIdx.x;
  int t = blockIdx.y;
  int tid = threadIdx.x;
  const float* l2 = l2_all + (long)t * 32768;
  const float* Apool = Apool_all + (long)t * 16384;
  r2row[tid] = r2_all[(long)t * 32768 + j * 256 + tid];
  a2s[tid] = a2_all[t * 256 + tid];
  __syncthreads();
#pragma unroll
  for (int p = tid; p < 512; p += 256) {
    int i = p >> 2, h = p & 3;
    const float* lr_ = l2 + i * 256 + h * 64;
    const float* rr_ = r2row + h * 64;
    const float* av_ = a2s + h * 64;
    float s = 0.f;
    for (int c = 0; c < 64; ++c) {
      float x = lr_[c] + rr_[c];
      s += (x > 0.f ? x : 0.2f * x) * av_[c];
    }
    sc[p] = (Apool[i * 128 + j] > 0.f) ? s : -1e9f;
  }
  __syncthreads();
  int h = tid >> 6, lane = tid & 63;
  float v0 = sc[lane * 4 + h], v1 = sc[(lane + 64) * 4 + h];
  float m = fmaxf(v0, v1);
#pragma unroll
  for (int sh = 1; sh < 64; sh <<= 1) m = fmaxf(m, __shfl_xor(m, sh, 64));
  float e0 = expf(v0 - m), e1 = expf(v1 - m);
  float s = e0 + e1;
#pragma unroll
  for (int sh = 1; sh < 64; sh <<= 1) s += __shfl_xor(s, sh, 64);
  float inv = 1.f / s;
  attn_out[(long)t * 65536 + (long)lane * 512 + j * 4 + h] = e0 * inv;
  attn_out[(long)t * 65536 + (long)(lane + 64) * 512 + j * 4 + h] = e1 * inv;
}

// ---------------- classifier ----------------
__global__ __launch_bounds__(256) void classifier(const float* __restrict__ p_all,
                                                  const float* __restrict__ Wcls,
                                                  const float* __restrict__ bcls,
                                                  float* __restrict__ out, int nrows) {
  int wid = threadIdx.x >> 6, lane = threadIdx.x & 63;
  int rrow = blockIdx.x * 4 + wid;
  if (rrow >= nrows) return;
  const float4 w = *(const float4*)(Wcls + lane * 4);
  const float4 x = *(const float4*)(p_all + (long)rrow * 256 + lane * 4);
  float s = x.x * w.x + x.y * w.y + x.z * w.z + x.w * w.w;
#pragma unroll
  for (int sh = 1; sh < 64; sh <<= 1) s += __shfl_xor(s, sh, 64);
  if (lane == 0) out[rrow] = 1.f / (1.f + expf(-(s + bcls[0])));
}

__global__ void finalize_loss(const float* __restrict__ red_buf, float* __restrict__ out896) {
  __shared__ float red[256];
  int t = threadIdx.x;
  red[t] = red_buf[t];
  __syncthreads();
  for (int sh = 128; sh > 0; sh >>= 1) {
    if (t < sh) red[t] += red[t + sh];
    __syncthreads();
  }
  if (t == 0) out896[0] = red[0] + red_buf[256];
}

// =====================================================================
extern "C" void kernel_launch(void* const* d_in, const int* in_sizes, int n_in,
                              void* d_out, int out_size, void* d_ws, size_t ws_size,
                              hipStream_t stream) {
  (void)in_sizes; (void)n_in; (void)out_size; (void)ws_size;
  const float* x_pkg  = (const float*)d_in[0];
  const float* x_tgt  = (const float*)d_in[1];
  const int* src_idx  = (const int*)d_in[2];
  const int* tgt_idx  = (const int*)d_in[3];
  const float* W1s    = (const float*)d_in[4];
  const float* W1t    = (const float*)d_in[5];
  const float* a1     = (const float*)d_in[6];
  const float* Wpkg   = (const float*)d_in[7];
  const float* Wassign= (const float*)d_in[8];
  const float* W2s    = (const float*)d_in[9];
  const float* W2t    = (const float*)d_in[10];
  const float* a2     = (const float*)d_in[11];
  const float* Wcls   = (const float*)d_in[12];
  const float* bcls   = (const float*)d_in[13];
  float* out = (float*)d_out;

  char* wp = (char*)d_ws;
  auto alloc = [&](size_t bytes) -> char* {
    char* r = wp;
    wp += (bytes + 255) & ~(size_t)255;
    return r;
  };
  // --- zero region (contiguous): p_buf, M_all, Apool, red_buf, counts ---
  float* p_buf   = (float*)alloc((size_t)7 * 32768 * 4);          // slot0=pkg, 1..6=types
  float* M_all   = (float*)alloc((size_t)7 * 16384 * 4);          // slots 0..5=types, 6=pkg
  float* Apool   = (float*)alloc((size_t)NTYPES * 16384 * 4);
  float* red_buf = (float*)alloc(257 * 4);
  int* counts    = (int*)alloc((size_t)NTYPES * NTGT * 4);
  long zero_n = ((char*)counts + (size_t)NTYPES * NTGT * 4 - (char*)p_buf) / 4;
  // --- rest ---
  int* offs      = (int*)alloc((size_t)NTYPES * (NTGT + 1) * 4);
  int* cursor    = (int*)alloc((size_t)NTYPES * NTGT * 4);
  int* eorder    = (int*)alloc((size_t)NTYPES * NEDGE * 4);
  ushortT* x_pkg_bf = (ushortT*)alloc((size_t)MP_PKG * KP_IN * 2);
  ushortT* x_t_bf   = (ushortT*)alloc((size_t)NTYPES * XSTR * 2);
  ushortT* WT_all   = (ushortT*)alloc((size_t)13 * WSTR * 2);     // 0..5 W1s, 6 Wpkg, 7..12 W1t
  ushortT* WassT    = (ushortT*)alloc((size_t)7 * 128 * 256 * 2); // slot0=pkg, 1..6=types
  ushortT* h_pkg_bf = (ushortT*)alloc((size_t)MP_PKG * 256 * 2);
  ushortT* l_bf     = (ushortT*)alloc((size_t)NTYPES * LSTR * 2);
  ushortT* r_bf     = (ushortT*)alloc((size_t)NTYPES * RSTR * 2);
  ushortT* h_t_bf   = (ushortT*)alloc((size_t)NTYPES * RSTR * 2);
  float* logits     = (float*)alloc((size_t)7 * LOGSTR * 4);      // slots 0..5=types, 6=pkg
  ushortT* S_all    = (ushortT*)alloc((size_t)7 * SSTR * 2);      // slots 0..5=types, 6=pkg
  float* l2r2       = (float*)alloc((size_t)12 * 32768 * 4);      // l2[6], then r2[6]
  float* ent_slots  = red_buf;
  float* loss_acc   = red_buf + 256;
  float* l2_all = l2r2;
  float* r2_all = l2r2 + (size_t)6 * 32768;

  dim3 blk(256);

  // 1. zero all atomic targets in one pass + zero pad rows of S_t / h_t
  zero_f32<<<dim3(512), blk, 0, stream>>>(p_buf, zero_n);
  zero_tails<<<dim3(30, NTYPES), blk, 0, stream>>>(S_all, h_t_bf);

  // 2-3. input conversions
  convert_pad<<<dim3((NPKG * (KP_IN / 4) + 255) / 256, 1), blk, 0, stream>>>(
      x_pkg, x_pkg_bf, NPKG, INDIM, KP_IN, 0, 0);
  convert_pad<<<dim3((NTGT * (KP_IN / 4) + 255) / 256, NTYPES), blk, 0, stream>>>(
      x_tgt, x_t_bf, NTGT, INDIM, KP_IN, (long)NTGT * INDIM, (long)XSTR);

  // 4-5. weight transposes
  wtrans13<<<dim3((256 * KP_IN + 255) / 256, 13), blk, 0, stream>>>(W1s, Wpkg, W1t, WT_all);
  wtransAss<<<dim3((128 * 256 + 255) / 256, 7), blk, 0, stream>>>(Wassign, WassT);

  // 6-8. CSR
  hist_kernel<<<dim3(391, NTYPES), blk, 0, stream>>>(tgt_idx, counts, NEDGE, NTGT);
  scan_kernel<<<dim3(NTYPES), dim3(1024), 0, stream>>>(counts, offs, cursor, NTGT);
  scatter_kernel<<<dim3(391, NTYPES), blk, 0, stream>>>(tgt_idx, cursor, eorder, NEDGE, NTGT);

  // 9. l-gemms (z=0..5) + h_pkg gemm (z=6), all A=x_pkg
  {
    MfmaBatch d{};
    for (int z = 0; z < 6; ++z) {
      d.A[z] = x_pkg_bf; d.BT[z] = WT_all + (size_t)z * WSTR;
      d.C[z] = l_bf + (size_t)z * LSTR; d.M[z] = NPKG; d.relu[z] = 0;
    }
    d.A[6] = x_pkg_bf; d.BT[6] = WT_all + (size_t)6 * WSTR;
    d.C[6] = h_pkg_bf; d.M[6] = NPKG; d.relu[6] = 1;
    d.A[7] = d.A[0]; d.BT[7] = d.BT[0]; d.C[7] = d.C[0]; d.M[7] = 0; d.relu[7] = 0;
    gemm_mfma_b<false><<<dim3(2, 157, 7), blk, 0, stream>>>(d, KP_IN, 256);
  }

  // 10. r-gemms (z=0..5)
  {
    MfmaBatch d{};
    for (int z = 0; z < 6; ++z) {
      d.A[z] = x_t_bf + (size_t)z * XSTR; d.BT[z] = WT_all + (size_t)(7 + z) * WSTR;
      d.C[z] = r_bf + (size_t)z * RSTR; d.M[z] = NTGT; d.relu[z] = 0;
    }
    for (int z = 6; z < 8; ++z) { d.A[z] = d.A[0]; d.BT[z] = d.BT[0]; d.C[z] = d.C[0]; d.M[z] = 0; d.relu[z] = 0; }
    gemm_mfma_b<false><<<dim3(2, 235, 6), blk, 0, stream>>>(d, KP_IN, 256);
  }

  // 11. conv1 (all types)
  conv1_agg<<<dim3(7500, NTYPES), blk, 0, stream>>>(l_bf, r_bf, a1, src_idx, eorder, offs, h_t_bf);

  // 12. assignment logits (z=0..5 types, z=6 pkg)
  {
    MfmaBatch d{};
    for (int z = 0; z < 6; ++z) {
      d.A[z] = h_t_bf + (size_t)z * RSTR; d.BT[z] = WassT + (size_t)(z + 1) * 128 * 256;
      d.C[z] = logits + (size_t)z * LOGSTR; d.M[z] = NTGT; d.relu[z] = 0;
    }
    d.A[6] = h_pkg_bf; d.BT[6] = WassT; d.C[6] = logits + (size_t)6 * LOGSTR;
    d.M[6] = NPKG; d.relu[6] = 0;
    d.A[7] = d.A[0]; d.BT[7] = d.BT[0]; d.C[7] = d.C[0]; d.M[7] = 0; d.relu[7] = 0;
    gemm_mfma_b<true><<<dim3(1, 235, 7), blk, 0, stream>>>(d, 256, 128);
  }

  // 13. softmax + entropy (z=0..6), 32 rows/block
  softmax_ent<<<dim3(938, 7), blk, 0, stream>>>(logits, S_all, ent_slots);

  // 14. pooled features P = S^T h (mats 0..5 types, 6 pkg) — MFMA TN
  {
    TnBatch d{};
    for (int m = 0; m < 6; ++m) {
      d.A[m] = S_all + (size_t)m * SSTR; d.B[m] = h_t_bf + (size_t)m * RSTR;
      d.C[m] = p_buf + (size_t)(m + 1) * 32768;
      d.rA[m] = nullptr; d.rB[m] = nullptr; d.N[m] = MP_TGT;  // pad rows are zeroed
    }
    d.A[6] = S_all + (size_t)6 * SSTR; d.B[6] = h_pkg_bf; d.C[6] = p_buf;
    d.rA[6] = nullptr; d.rB[6] = nullptr; d.N[6] = NPKG;
    d.A[7] = d.A[0]; d.B[7] = d.B[0]; d.C[7] = d.C[0]; d.rA[7] = nullptr; d.rB[7] = nullptr; d.N[7] = 0;
    gemm_tn_mfma<256><<<dim3(2, 1, 7 * 30), blk, 0, stream>>>(d, 1024, 30);
  }

  // 15. M = S^T S (mats 0..5 types, 6 pkg) — MFMA TN
  {
    TnBatch d{};
    for (int m = 0; m < 7; ++m) {
      const ushortT* S = S_all + (size_t)m * SSTR;
      d.A[m] = S; d.B[m] = S; d.C[m] = M_all + (size_t)m * 16384;
      d.rA[m] = nullptr; d.rB[m] = nullptr; d.N[m] = (m == 6) ? NPKG : MP_TGT;
    }
    d.A[7] = d.A[0]; d.B[7] = d.B[0]; d.C[7] = d.C[0]; d.rA[7] = nullptr; d.rB[7] = nullptr; d.N[7] = 0;
    gemm_tn_mfma<128><<<dim3(1, 1, 7 * 30), blk, 0, stream>>>(d, 1024, 30);
  }

  // 16. Apool = gathered S_pkg^T S_t over edges (mats 0..5) — MFMA TN + gather
  {
    TnBatch d{};
    for (int m = 0; m < 6; ++m) {
      d.A[m] = S_all + (size_t)6 * SSTR; d.B[m] = S_all + (size_t)m * SSTR;
      d.C[m] = Apool + (size_t)m * 16384;
      d.rA[m] = src_idx + (long)m * NEDGE; d.rB[m] = tgt_idx + (long)m * NEDGE;
      d.N[m] = NEDGE;
    }
    for (int m = 6; m < 8; ++m) { d.A[m] = d.A[0]; d.B[m] = d.B[0]; d.C[m] = d.C[0]; d.rA[m] = nullptr; d.rB[m] = nullptr; d.N[m] = 0; }
    gemm_tn_mfma<128><<<dim3(1, 1, 6 * 98), blk, 0, stream>>>(d, 1024, 98);
  }

  // 17. link losses
  link_kernel<<<dim3(6), blk, 0, stream>>>(Apool, M_all, (float)NEDGE,
                                           1.f / ((float)NPKG * (float)NTGT), loss_acc);

  // 18-19. conv2
  conv2_gemm<<<dim3(2, 1, 12), blk, 0, stream>>>(p_buf, W2s, W2t, l2r2);
  conv2_attn<<<dim3(128, NTYPES), blk, 0, stream>>>(l2_all, r2_all, Apool, a2, out + 897);

  // 20-21. classifier + loss
  classifier<<<dim3(224), blk, 0, stream>>>(p_buf, Wcls, bcls, out, 896);
  finalize_loss<<<dim3(1), blk, 0, stream>>>(red_buf, out + 896);
}

// Round 4
// 1237.716 us; speedup vs baseline: 1.6622x; 1.0295x over previous
//
#include <hip/hip_runtime.h>
#include <math.h>

#define NPKG   20000
#define NTGT   30000
#define NEDGE  100000
#define NTYPES 6
#define INDIM  400
#define KP_IN  416      // INDIM padded to mult of 32
#define MP_PKG 20096    // 157*128
#define MP_TGT 30080    // 235*128

#define LSTR   ((size_t)MP_PKG * 256)   // l_bf per-type stride (elems)
#define RSTR   ((size_t)MP_TGT * 256)   // r_bf / h_t per-type stride
#define XSTR   ((size_t)MP_TGT * KP_IN) // x_t_bf per-type stride
#define LOGSTR ((size_t)MP_TGT * 128)   // logits per-slot stride (f32)
#define SSTR   ((size_t)MP_TGT * 128)   // S per-slot stride (bf16)
#define WSTR   ((size_t)256 * KP_IN)    // weight slot stride

typedef unsigned short ushortT;
typedef unsigned int uintT;
typedef __attribute__((ext_vector_type(8))) short bf16x8;
typedef __attribute__((ext_vector_type(8))) short short8b;
typedef __attribute__((ext_vector_type(4))) float f32x4;

__device__ __forceinline__ float lrelu(float x) { return x > 0.f ? x : 0.2f * x; }
__device__ __forceinline__ float b2f(ushortT u) {
  union { unsigned int i; float f; } x; x.i = ((unsigned int)u) << 16; return x.f;
}
__device__ __forceinline__ ushortT f2b(float f) {
  unsigned int u = __float_as_uint(f);
  unsigned int r = (u + 0x7FFFu + ((u >> 16) & 1u)) >> 16;
  return (ushortT)r;
}

#define GLL16(g, l)                                                            \
  __builtin_amdgcn_global_load_lds(                                            \
      (const __attribute__((address_space(1))) void*)(g),                      \
      (__attribute__((address_space(3))) void*)(l), 16, 0, 0)

// ---------------- utility ----------------
__global__ void zero_f32(float* __restrict__ p, long n) {
  long i = blockIdx.x * 256 + threadIdx.x, st = (long)gridDim.x * 256;
  for (; i < n; i += st) p[i] = 0.f;
}

// zero pad rows [30000,30080) of S (128 cols) and h_t (256 cols), per type
__global__ void zero_tails(ushortT* __restrict__ S_all, ushortT* __restrict__ h_t) {
  int t = blockIdx.y;
  int i = blockIdx.x * 256 + threadIdx.x;  // 0..7679, each handles 4 elems
  ushort4 z = {0, 0, 0, 0};
  if (i < 2560) {                          // 80*128/4 -> S
    int r = i >> 5, c = (i & 31) * 4;
    *(ushort4*)(S_all + (size_t)t * SSTR + (size_t)(30000 + r) * 128 + c) = z;
  } else if (i < 7680) {                   // 80*256/4 -> h_t
    int k = i - 2560;
    int r = k >> 6, c = (k & 63) * 4;
    *(ushort4*)(h_t + (size_t)t * RSTR + (size_t)(30000 + r) * 256 + c) = z;
  }
}

// f32 [M,K] -> bf16 [*, Kp]; batched over blockIdx.y via strides
__global__ void convert_pad(const float* __restrict__ src, ushortT* __restrict__ dst,
                            int M, int K, int Kp, long srcStride, long dstStride) {
  long z = blockIdx.y;
  const float* s = src + z * srcStride;
  ushortT* d = dst + z * dstStride;
  int idx = blockIdx.x * 256 + threadIdx.x;
  int q = Kp >> 2;
  int row = idx / q, c4 = (idx - row * q) * 4;
  if (row >= M) return;
  float4 v = make_float4(0.f, 0.f, 0.f, 0.f);
  if (c4 < K) v = *(const float4*)(s + (size_t)row * K + c4);  // K mult of 4
  ushort4 o;
  o.x = f2b(v.x); o.y = f2b(v.y); o.z = f2b(v.z); o.w = f2b(v.w);
  *(ushort4*)(d + (size_t)row * Kp + c4) = o;
}

// 13-way batched weight transpose: slots 0..5 = W1s[t], 6 = Wpkg, 7..12 = W1t[t]
__global__ void wtrans13(const float* __restrict__ W1s, const float* __restrict__ Wpkg,
                         const float* __restrict__ W1t, ushortT* __restrict__ WT) {
  int z = blockIdx.y;
  const float* Wb = (z < 6) ? (W1s + (size_t)z * INDIM * 256)
                  : (z == 6) ? Wpkg
                  : (W1t + (size_t)(z - 7) * INDIM * 256);
  ushortT* WTb = WT + (size_t)z * WSTR;
  int idx = blockIdx.x * 256 + threadIdx.x;
  if (idx >= 256 * KP_IN) return;
  int n = idx / KP_IN, k = idx - n * KP_IN;
  WTb[idx] = (k < INDIM) ? f2b(Wb[(size_t)k * 256 + n]) : (ushortT)0;
}

// Wassign [7][256][128] -> [7][128][256] bf16
__global__ void wtransAss(const float* __restrict__ W, ushortT* __restrict__ WT) {
  int z = blockIdx.y;
  const float* Wb = W + (size_t)z * 256 * 128;
  ushortT* WTb = WT + (size_t)z * 128 * 256;
  int idx = blockIdx.x * 256 + threadIdx.x;
  if (idx >= 128 * 256) return;
  int n = idx >> 8, k = idx & 255;
  WTb[idx] = f2b(Wb[(size_t)k * 128 + n]);
}

// ---------------- batched MFMA GEMM ----------------
struct MfmaBatch {
  const ushortT* A[8];
  const ushortT* BT[8];
  void* C[8];
  int M[8];
  int relu[8];
};

template<bool WF32>
__global__ __launch_bounds__(256) void gemm_mfma_b(MfmaBatch d, int Kp, int N) {
  const int z = blockIdx.z;
  const int M = d.M[z];
  const int m0 = blockIdx.y * 128;
  if (m0 >= M) return;
  const ushortT* A = d.A[z];
  const ushortT* BT = d.BT[z];
  const int relu = d.relu[z];
  __shared__ ushortT As[128 * 32];
  __shared__ ushortT Bs[128 * 32];
  const int tid = threadIdx.x;
  const int wave = tid >> 6, lane = tid & 63;
  const int lr = lane & 15, hk = lane >> 4;
  const int am = (wave >> 1) * 64;
  const int bn = (wave & 1) * 64;
  const int n0 = blockIdx.x * 128;

  const int row1 = tid >> 2, cg = (tid & 3) * 8;
  const int row2 = row1 + 64;
  ushortT* ldsA1 = As + ((tid >> 6) << 9);
  ushortT* ldsA2 = As + 2048 + ((tid >> 6) << 9);
  ushortT* ldsB1 = Bs + ((tid >> 6) << 9);
  ushortT* ldsB2 = Bs + 2048 + ((tid >> 6) << 9);
  const ushortT* gA1 = A + (size_t)(m0 + row1) * Kp + cg;
  const ushortT* gA2 = A + (size_t)(m0 + row2) * Kp + cg;
  const ushortT* gB1 = BT + (size_t)(n0 + row1) * Kp + cg;
  const ushortT* gB2 = BT + (size_t)(n0 + row2) * Kp + cg;

  f32x4 acc[4][4];
#pragma unroll
  for (int i = 0; i < 4; ++i)
#pragma unroll
    for (int j = 0; j < 4; ++j) acc[i][j] = (f32x4)(0.f);

  const int nk = Kp >> 5;
  for (int kt = 0; kt < nk; ++kt) {
    const int k0 = kt << 5;
    GLL16(gA1 + k0, ldsA1);
    GLL16(gA2 + k0, ldsA2);
    GLL16(gB1 + k0, ldsB1);
    GLL16(gB2 + k0, ldsB2);
    __syncthreads();
    bf16x8 af[4], bfr[4];
#pragma unroll
    for (int i = 0; i < 4; ++i)
      af[i] = *(const bf16x8*)(As + (size_t)(am + i * 16 + lr) * 32 + hk * 8);
#pragma unroll
    for (int j = 0; j < 4; ++j)
      bfr[j] = *(const bf16x8*)(Bs + (size_t)(bn + j * 16 + lr) * 32 + hk * 8);
#pragma unroll
    for (int i = 0; i < 4; ++i)
#pragma unroll
      for (int j = 0; j < 4; ++j)
        acc[i][j] = __builtin_amdgcn_mfma_f32_16x16x32_bf16(af[i], bfr[j], acc[i][j], 0, 0, 0);
    __syncthreads();
  }

#pragma unroll
  for (int i = 0; i < 4; ++i) {
#pragma unroll
    for (int reg = 0; reg < 4; ++reg) {
      int row = m0 + am + i * 16 + hk * 4 + reg;
      if (row < M) {
#pragma unroll
        for (int j = 0; j < 4; ++j) {
          int col = n0 + bn + j * 16 + lr;
          float v = acc[i][j][reg];
          if (relu) v = fmaxf(v, 0.f);
          if (WF32) ((float*)d.C[z])[(size_t)row * N + col] = v;
          else      ((ushortT*)d.C[z])[(size_t)row * N + col] = f2b(v);
        }
      }
    }
  }
}

// ---------------- batched TN GEMM via MFMA (C = A^T B, split-K atomic) ----------------
struct TnBatch {
  const ushortT* A[8];
  const ushortT* B[8];
  float* C[8];
  const int* rA[8];
  const int* rB[8];
  int N[8];
};

template<int K2>
__global__ __launch_bounds__(256) void gemm_tn_mfma(TnBatch d, int chunk, int nchunk) {
  const int mat = blockIdx.z / nchunk;
  const int ci = blockIdx.z - mat * nchunk;
  const int N = d.N[mat];
  const int kbeg = ci * chunk;
  if (kbeg >= N) return;
  const int kend = min(N, kbeg + chunk);
  const ushortT* __restrict__ A = d.A[mat];
  const ushortT* __restrict__ B = d.B[mat];
  const int* __restrict__ rA = d.rA[mat];
  const int* __restrict__ rB = d.rB[mat];
  float* __restrict__ C = d.C[mat];
  const int n0 = (K2 == 256) ? blockIdx.x * 128 : 0;

  __shared__ uintT AtU[2048];
  __shared__ uintT BtU[2048];
  const ushortT* At = (const ushortT*)AtU;
  const ushortT* Bt = (const ushortT*)BtU;

  const int tid = threadIdx.x;
  const int kp = tid >> 4;          // 0..15
  const int mo8 = tid & 15;         // 0..15
  const int mh = mo8 >> 1;          // = m>>4 of staged elems
  const int mlo = (mo8 & 1) * 8;    // m&15 base
  const uintT wbase = (uintT)mh * 256 + (uintT)(kp >> 2) * 64 + (uintT)(kp & 3);
  const int wave = tid >> 6, lane = tid & 63;
  const int lr = lane & 15, hk = lane >> 4;
  const int wm = wave >> 1, wn = wave & 1;
  int offA[4], offB[4];
#pragma unroll
  for (int i = 0; i < 4; ++i) {
    int Rm = wm * 4 + i, Rn = wn * 4 + i;
    offA[i] = Rm * 512 + hk * 128 + (lr ^ Rm) * 8;
    offB[i] = Rn * 512 + hk * 128 + (lr ^ Rn) * 8;
  }

  f32x4 acc[4][4];
#pragma unroll
  for (int i = 0; i < 4; ++i)
#pragma unroll
    for (int j = 0; j < 4; ++j) acc[i][j] = (f32x4)(0.f);

  for (int k0 = kbeg; k0 < kend; k0 += 32) {
    const int r0 = k0 + kp * 2;
    int ia0, ia1, ib0, ib1;
    if (rA) { int2 v = *(const int2*)(rA + r0); ia0 = v.x; ia1 = v.y; }
    else    { ia0 = r0; ia1 = r0 + 1; }
    if (rB) { int2 v = *(const int2*)(rB + r0); ib0 = v.x; ib1 = v.y; }
    else    { ib0 = r0; ib1 = r0 + 1; }
    bf16x8 a0 = *(const bf16x8*)(A + (size_t)ia0 * 128 + mo8 * 8);
    bf16x8 a1 = *(const bf16x8*)(A + (size_t)ia1 * 128 + mo8 * 8);
    bf16x8 b0, b1;
    if (K2 == 256) {
      b0 = *(const bf16x8*)(B + (size_t)ib0 * 256 + n0 + mo8 * 8);
      b1 = *(const bf16x8*)(B + (size_t)ib1 * 256 + n0 + mo8 * 8);
    } else {
      b0 = *(const bf16x8*)(B + (size_t)ib0 * 128 + mo8 * 8);
      b1 = *(const bf16x8*)(B + (size_t)ib1 * 128 + mo8 * 8);
    }
#pragma unroll
    for (int j = 0; j < 8; ++j) {
      uintT off = wbase + (uintT)((mlo + j) ^ mh) * 4;
      AtU[off] = (uintT)(ushortT)a0[j] | ((uintT)(ushortT)a1[j] << 16);
      BtU[off] = (uintT)(ushortT)b0[j] | ((uintT)(ushortT)b1[j] << 16);
    }
    __syncthreads();
    bf16x8 af[4], bfr[4];
#pragma unroll
    for (int i = 0; i < 4; ++i) af[i] = *(const bf16x8*)(At + offA[i]);
#pragma unroll
    for (int j = 0; j < 4; ++j) bfr[j] = *(const bf16x8*)(Bt + offB[j]);
#pragma unroll
    for (int i = 0; i < 4; ++i)
#pragma unroll
      for (int j = 0; j < 4; ++j)
        acc[i][j] = __builtin_amdgcn_mfma_f32_16x16x32_bf16(af[i], bfr[j], acc[i][j], 0, 0, 0);
    __syncthreads();
  }

#pragma unroll
  for (int i = 0; i < 4; ++i) {
    int mbase = wm * 64 + i * 16 + hk * 4;
#pragma unroll
    for (int reg = 0; reg < 4; ++reg) {
#pragma unroll
      for (int j = 0; j < 4; ++j) {
        int n = n0 + wn * 64 + j * 16 + lr;
        atomicAdd(&C[(size_t)(mbase + reg) * K2 + n], acc[i][j][reg]);
      }
    }
  }
}

// ---------------- CSR build ----------------
__global__ void hist_kernel(const int* __restrict__ tgt, int* __restrict__ counts,
                            int nE, int ntgt) {
  int t = blockIdx.y;
  int e = blockIdx.x * 256 + threadIdx.x;
  if (e < nE) atomicAdd(&counts[t * ntgt + tgt[(long)t * nE + e]], 1);
}

__global__ __launch_bounds__(1024) void scan_kernel(const int* __restrict__ counts_all,
                                                    int* __restrict__ offs_all,
                                                    int* __restrict__ cursor_all, int n) {
  __shared__ int lsum[1024];
  int ty = blockIdx.x;
  const int* counts = counts_all + (long)ty * n;
  int* offs = offs_all + (long)ty * (n + 1);
  int* cursor = cursor_all + (long)ty * n;
  int t = threadIdx.x;
  int chunk = (n + 1023) >> 10;
  int base = t * chunk;
  int s = 0;
  for (int i = 0; i < chunk; ++i) {
    int idx = base + i;
    if (idx < n) s += counts[idx];
  }
  lsum[t] = s;
  __syncthreads();
  for (int off = 1; off < 1024; off <<= 1) {
    int v = (t >= off) ? lsum[t - off] : 0;
    __syncthreads();
    lsum[t] += v;
    __syncthreads();
  }
  int run = lsum[t] - s;
  for (int i = 0; i < chunk; ++i) {
    int idx = base + i;
    if (idx < n) {
      offs[idx] = run;
      cursor[idx] = run;
      run += counts[idx];
    }
  }
  if (t == 1023) offs[n] = lsum[1023];
}

// writes SOURCE ids in CSR order (srcs), removing one indirection from conv1
__global__ void scatter_kernel(const int* __restrict__ tgt, const int* __restrict__ src,
                               int* __restrict__ cursor, int* __restrict__ srcs,
                               int nE, int ntgt) {
  int t = blockIdx.y;
  int e = blockIdx.x * 256 + threadIdx.x;
  if (e < nE) {
    int tv = tgt[(long)t * nE + e];
    int p = atomicAdd(&cursor[t * ntgt + tv], 1);
    srcs[(long)t * nE + p] = src[(long)t * nE + e];
  }
}

// ---------------- conv1: fused GATv2 (bf16 in/out), batched over type ----------------
// v2: srcs[] holds source ids in CSR order. 64 edges' ids loaded cooperatively
// (one coalesced load), broadcast via shfl; l-row gather software-pipelined
// one iteration ahead so the gather latency hides under score/exp/accumulate.
__global__ __launch_bounds__(256) void conv1_agg(const ushortT* __restrict__ l_all,
                                                 const ushortT* __restrict__ r_all,
                                                 const float* __restrict__ a1,
                                                 const int* __restrict__ srcs_all,
                                                 const int* __restrict__ offs_all,
                                                 ushortT* __restrict__ h_all) {
  int t = blockIdx.y;
  const ushortT* l = l_all + (size_t)t * LSTR;
  const ushortT* r = r_all + (size_t)t * RSTR;
  const float* a1t = a1 + t * 256;
  const int* srcs = srcs_all + (long)t * NEDGE;
  const int* offs = offs_all + (long)t * (NTGT + 1);
  ushortT* hout = h_all + (size_t)t * RSTR;

  int wid = threadIdx.x >> 6, lane = threadIdx.x & 63;
  int v = blockIdx.x * 4 + wid;
  if (v >= NTGT) return;
  ushort4 ru = *(const ushort4*)(r + (size_t)v * 256 + lane * 4);
  float rx = b2f(ru.x), ry = b2f(ru.y), rz = b2f(ru.z), rw = b2f(ru.w);
  const float4 aa = *(const float4*)(a1t + lane * 4);
  int beg = offs[v], end = offs[v + 1];
  float ax = 0.f, ay = 0.f, az = 0.f, aw = 0.f, den = 0.f;

  for (int cbeg = beg; cbeg < end; cbeg += 64) {
    int cnt = min(64, end - cbeg);
    int sidx = (lane < cnt) ? srcs[cbeg + lane] : 0;
    int u0 = __shfl(sidx, 0, 64);
    ushort4 lu = *(const ushort4*)(l + (size_t)u0 * 256 + lane * 4);
    for (int q = 0; q < cnt; ++q) {
      ushort4 cur = lu;
      if (q + 1 < cnt) {
        int un = __shfl(sidx, q + 1, 64);
        lu = *(const ushort4*)(l + (size_t)un * 256 + lane * 4);
      }
      float lx = b2f(cur.x), ly = b2f(cur.y), lz = b2f(cur.z), lw = b2f(cur.w);
      float s = lrelu(lx + rx) * aa.x + lrelu(ly + ry) * aa.y +
                lrelu(lz + rz) * aa.z + lrelu(lw + rw) * aa.w;
#pragma unroll
      for (int m = 1; m < 16; m <<= 1) s += __shfl_xor(s, m, 64);
      float w = expf(s);
      ax += w * lx; ay += w * ly; az += w * lz; aw += w * lw;
      den += w;
    }
  }
  float inv = (end > beg) ? 1.f / den : 0.f;
  ushort4 o;
  o.x = f2b(fmaxf(ax * inv, 0.f));
  o.y = f2b(fmaxf(ay * inv, 0.f));
  o.z = f2b(fmaxf(az * inv, 0.f));
  o.w = f2b(fmaxf(aw * inv, 0.f));
  *(ushort4*)(hout + (size_t)v * 256 + lane * 4) = o;
}

// ---------------- softmax (f32 logits -> bf16 S) + entropy, batched z=7 ----------------
// v2: 8 lanes per row, 16 elems/lane. 4 independent float4 loads per thread,
// 3-level shuffle reduces, packed 16-bf16 store. Pad rows masked (loads are
// in-bounds: every slot is MP_TGT-row strided).
__global__ __launch_bounds__(256) void softmax_ent(const float* __restrict__ logits_all,
                                                   ushortT* __restrict__ S_all,
                                                   float* __restrict__ ent_slots) {
  int z = blockIdx.y;
  int nrows = (z == 6) ? NPKG : NTGT;
  if (blockIdx.x * 32 >= nrows) return;
  float inv_n = 1.f / (float)nrows;
  const float* logits = logits_all + (size_t)z * LOGSTR;
  ushortT* Sb = S_all + (size_t)z * SSTR;

  int wid = threadIdx.x >> 6, lane = threadIdx.x & 63;
  int rloc = lane >> 3, seg = lane & 7;
  int v = blockIdx.x * 32 + wid * 8 + rloc;
  bool valid = v < nrows;

  const float* row = logits + (size_t)v * 128 + seg * 16;
  f32x4 x0 = *(const f32x4*)(row);
  f32x4 x1 = *(const f32x4*)(row + 4);
  f32x4 x2 = *(const f32x4*)(row + 8);
  f32x4 x3 = *(const f32x4*)(row + 12);

  float m01 = fmaxf(fmaxf(x0.x, x0.y), fmaxf(x0.z, x0.w));
  float m11 = fmaxf(fmaxf(x1.x, x1.y), fmaxf(x1.z, x1.w));
  float m21 = fmaxf(fmaxf(x2.x, x2.y), fmaxf(x2.z, x2.w));
  float m31 = fmaxf(fmaxf(x3.x, x3.y), fmaxf(x3.z, x3.w));
  float m = fmaxf(fmaxf(m01, m11), fmaxf(m21, m31));
#pragma unroll
  for (int sh = 1; sh < 8; sh <<= 1) m = fmaxf(m, __shfl_xor(m, sh, 64));

  f32x4 e0, e1, e2, e3;
  float s = 0.f, tt = 0.f;
#pragma unroll
  for (int q = 0; q < 4; ++q) {
    f32x4 xq = (q == 0) ? x0 : (q == 1) ? x1 : (q == 2) ? x2 : x3;
    f32x4 eq;
#pragma unroll
    for (int c = 0; c < 4; ++c) {
      float d = xq[c] - m;
      float e = expf(d);
      eq[c] = e;
      s += e;
      tt += e * d;
    }
    if (q == 0) e0 = eq; else if (q == 1) e1 = eq; else if (q == 2) e2 = eq; else e3 = eq;
  }
#pragma unroll
  for (int sh = 1; sh < 8; sh <<= 1) {
    s += __shfl_xor(s, sh, 64);
    tt += __shfl_xor(tt, sh, 64);
  }
  float inv = 1.f / s;

  if (valid) {
    short8b lo, hi;
#pragma unroll
    for (int c = 0; c < 4; ++c) {
      lo[c]     = (short)f2b(e0[c] * inv);
      lo[c + 4] = (short)f2b(e1[c] * inv);
      hi[c]     = (short)f2b(e2[c] * inv);
      hi[c + 4] = (short)f2b(e3[c] * inv);
    }
    ushortT* op = Sb + (size_t)v * 128 + seg * 16;
    *(short8b*)(op) = lo;
    *(short8b*)(op + 8) = hi;
  }

  float val = (valid && seg == 0) ? (logf(s) - tt / s) * inv_n : 0.f;
#pragma unroll
  for (int sh = 1; sh < 64; sh <<= 1) val += __shfl_xor(val, sh, 64);
  if (lane == 0) atomicAdd(&ent_slots[blockIdx.x & 255], val);
}

// ---------------- link loss, batched grid(6) ----------------
__global__ __launch_bounds__(256) void link_kernel(const float* __restrict__ Apool_all,
                                                   const float* __restrict__ M_all,
                                                   float Ef, float scale,
                                                   float* __restrict__ loss) {
  __shared__ float red[256];
  int ty = blockIdx.x;
  const float* Apool = Apool_all + (size_t)ty * 16384;
  const float* Mp = M_all + (size_t)6 * 16384;
  const float* Mt = M_all + (size_t)ty * 16384;
  int t = threadIdx.x;
  float s = 0.f;
  for (int i = t; i < 16384; i += 256) s += Mp[i] * Mt[i];
  if (t < 128) s -= 2.f * Apool[t * 129];
  red[t] = s;
  __syncthreads();
  for (int sh = 128; sh > 0; sh >>= 1) {
    if (t < sh) red[t] += red[t + sh];
    __syncthreads();
  }
  if (t == 0) {
    float norm2 = Ef + red[0];
    atomicAdd(loss, sqrtf(fmaxf(norm2, 0.f) + 1e-12f) * scale);
  }
}

// ---------------- conv2 GEMMs, one launch z=12 ----------------
__global__ __launch_bounds__(256) void conv2_gemm(const float* __restrict__ p_buf,
                                                  const float* __restrict__ W2s,
                                                  const float* __restrict__ W2t,
                                                  float* __restrict__ l2r2) {
  const int z = blockIdx.z;
  const int sel = z / 6, t = z - sel * 6;
  const float* A = p_buf + (sel ? (size_t)(t + 1) * 32768 : 0);
  const float* B = (sel ? W2t : W2s) + (size_t)t * 65536;
  float* C = l2r2 + (size_t)sel * 196608 + (size_t)t * 32768;
  const int M = 128, K = 256, N = 256;
  __shared__ __align__(16) float As[16][136];
  __shared__ __align__(16) float Bs[16][136];
  const int tid = threadIdx.x;
  const int tx = tid & 15, ty = tid >> 4;
  const int n0 = blockIdx.x * 128;
  float acc[8][8];
#pragma unroll
  for (int i = 0; i < 8; ++i)
#pragma unroll
    for (int j = 0; j < 8; ++j) acc[i][j] = 0.f;
  for (int k0 = 0; k0 < K; k0 += 16) {
#pragma unroll
    for (int i = 0; i < 8; ++i) {
      int idx = tid + i * 256;
      int rr = idx >> 4, kk = idx & 15;
      As[kk][rr] = (rr < M) ? A[(size_t)rr * K + (k0 + kk)] : 0.f;
    }
#pragma unroll
    for (int i = 0; i < 8; ++i) {
      int idx = tid + i * 256;
      int kk = idx >> 7, nn = idx & 127;
      Bs[kk][nn] = B[(size_t)(k0 + kk) * N + (n0 + nn)];
    }
    __syncthreads();
#pragma unroll
    for (int kk = 0; kk < 16; ++kk) {
      float4 a0 = *(const float4*)&As[kk][ty * 8];
      float4 a1 = *(const float4*)&As[kk][ty * 8 + 4];
      float4 b0 = *(const float4*)&Bs[kk][tx * 8];
      float4 b1 = *(const float4*)&Bs[kk][tx * 8 + 4];
      float av[8] = {a0.x, a0.y, a0.z, a0.w, a1.x, a1.y, a1.z, a1.w};
      float bv[8] = {b0.x, b0.y, b0.z, b0.w, b1.x, b1.y, b1.z, b1.w};
#pragma unroll
      for (int i = 0; i < 8; ++i)
#pragma unroll
        for (int j = 0; j < 8; ++j) acc[i][j] += av[i] * bv[j];
    }
    __syncthreads();
  }
#pragma unroll
  for (int i = 0; i < 8; ++i) {
    int m = ty * 8 + i;
    if (m < M) {
#pragma unroll
      for (int j = 0; j < 8; ++j)
        C[(size_t)m * N + n0 + tx * 8 + j] = acc[i][j];
    }
  }
}

// ---------------- conv2 dense attention ----------------
__global__ __launch_bounds__(256) void conv2_attn(const float* __restrict__ l2_all,
                                                  const float* __restrict__ r2_all,
                                                  const float* __restrict__ Apool_all,
                                                  const float* __restrict__ a2_all,
                                                  float* __restrict__ attn_out) {
  __shared__ float r2row[256], a2s[256], sc[512];
  int j = blockIdx.x;
  int t = blockIdx.y;
  int tid = threadIdx.x;
  const float* l2 = l2_all + (long)t * 32768;
  const float* Apool = Apool_all + (long)t * 16384;
  r2row[tid] = r2_all[(long)t * 32768 + j * 256 + tid];
  a2s[tid] = a2_all[t * 256 + tid];
  __syncthreads();
#pragma unroll
  for (int p = tid; p < 512; p += 256) {
    int i = p >> 2, h = p & 3;
    const float* lr_ = l2 + i * 256 + h * 64;
    const float* rr_ = r2row + h * 64;
    const float* av_ = a2s + h * 64;
    float s = 0.f;
    for (int c = 0; c < 64; ++c) {
      float x = lr_[c] + rr_[c];
      s += (x > 0.f ? x : 0.2f * x) * av_[c];
    }
    sc[p] = (Apool[i * 128 + j] > 0.f) ? s : -1e9f;
  }
  __syncthreads();
  int h = tid >> 6, lane = tid & 63;
  float v0 = sc[lane * 4 + h], v1 = sc[(lane + 64) * 4 + h];
  float m = fmaxf(v0, v1);
#pragma unroll
  for (int sh = 1; sh < 64; sh <<= 1) m = fmaxf(m, __shfl_xor(m, sh, 64));
  float e0 = expf(v0 - m), e1 = expf(v1 - m);
  float s = e0 + e1;
#pragma unroll
  for (int sh = 1; sh < 64; sh <<= 1) s += __shfl_xor(s, sh, 64);
  float inv = 1.f / s;
  attn_out[(long)t * 65536 + (long)lane * 512 + j * 4 + h] = e0 * inv;
  attn_out[(long)t * 65536 + (long)(lane + 64) * 512 + j * 4 + h] = e1 * inv;
}

// ---------------- classifier ----------------
__global__ __launch_bounds__(256) void classifier(const float* __restrict__ p_all,
                                                  const float* __restrict__ Wcls,
                                                  const float* __restrict__ bcls,
                                                  float* __restrict__ out, int nrows) {
  int wid = threadIdx.x >> 6, lane = threadIdx.x & 63;
  int rrow = blockIdx.x * 4 + wid;
  if (rrow >= nrows) return;
  const float4 w = *(const float4*)(Wcls + lane * 4);
  const float4 x = *(const float4*)(p_all + (long)rrow * 256 + lane * 4);
  float s = x.x * w.x + x.y * w.y + x.z * w.z + x.w * w.w;
#pragma unroll
  for (int sh = 1; sh < 64; sh <<= 1) s += __shfl_xor(s, sh, 64);
  if (lane == 0) out[rrow] = 1.f / (1.f + expf(-(s + bcls[0])));
}

__global__ void finalize_loss(const float* __restrict__ red_buf, float* __restrict__ out896) {
  __shared__ float red[256];
  int t = threadIdx.x;
  red[t] = red_buf[t];
  __syncthreads();
  for (int sh = 128; sh > 0; sh >>= 1) {
    if (t < sh) red[t] += red[t + sh];
    __syncthreads();
  }
  if (t == 0) out896[0] = red[0] + red_buf[256];
}

// =====================================================================
extern "C" void kernel_launch(void* const* d_in, const int* in_sizes, int n_in,
                              void* d_out, int out_size, void* d_ws, size_t ws_size,
                              hipStream_t stream) {
  (void)in_sizes; (void)n_in; (void)out_size; (void)ws_size;
  const float* x_pkg  = (const float*)d_in[0];
  const float* x_tgt  = (const float*)d_in[1];
  const int* src_idx  = (const int*)d_in[2];
  const int* tgt_idx  = (const int*)d_in[3];
  const float* W1s    = (const float*)d_in[4];
  const float* W1t    = (const float*)d_in[5];
  const float* a1     = (const float*)d_in[6];
  const float* Wpkg   = (const float*)d_in[7];
  const float* Wassign= (const float*)d_in[8];
  const float* W2s    = (const float*)d_in[9];
  const float* W2t    = (const float*)d_in[10];
  const float* a2     = (const float*)d_in[11];
  const float* Wcls   = (const float*)d_in[12];
  const float* bcls   = (const float*)d_in[13];
  float* out = (float*)d_out;

  char* wp = (char*)d_ws;
  auto alloc = [&](size_t bytes) -> char* {
    char* r = wp;
    wp += (bytes + 255) & ~(size_t)255;
    return r;
  };
  // --- zero region (contiguous): p_buf, M_all, Apool, red_buf, counts ---
  float* p_buf   = (float*)alloc((size_t)7 * 32768 * 4);          // slot0=pkg, 1..6=types
  float* M_all   = (float*)alloc((size_t)7 * 16384 * 4);          // slots 0..5=types, 6=pkg
  float* Apool   = (float*)alloc((size_t)NTYPES * 16384 * 4);
  float* red_buf = (float*)alloc(257 * 4);
  int* counts    = (int*)alloc((size_t)NTYPES * NTGT * 4);
  long zero_n = ((char*)counts + (size_t)NTYPES * NTGT * 4 - (char*)p_buf) / 4;
  // --- rest ---
  int* offs      = (int*)alloc((size_t)NTYPES * (NTGT + 1) * 4);
  int* cursor    = (int*)alloc((size_t)NTYPES * NTGT * 4);
  int* srcs      = (int*)alloc((size_t)NTYPES * NEDGE * 4);
  ushortT* x_pkg_bf = (ushortT*)alloc((size_t)MP_PKG * KP_IN * 2);
  ushortT* x_t_bf   = (ushortT*)alloc((size_t)NTYPES * XSTR * 2);
  ushortT* WT_all   = (ushortT*)alloc((size_t)13 * WSTR * 2);     // 0..5 W1s, 6 Wpkg, 7..12 W1t
  ushortT* WassT    = (ushortT*)alloc((size_t)7 * 128 * 256 * 2); // slot0=pkg, 1..6=types
  ushortT* h_pkg_bf = (ushortT*)alloc((size_t)MP_PKG * 256 * 2);
  ushortT* l_bf     = (ushortT*)alloc((size_t)NTYPES * LSTR * 2);
  ushortT* r_bf     = (ushortT*)alloc((size_t)NTYPES * RSTR * 2);
  ushortT* h_t_bf   = (ushortT*)alloc((size_t)NTYPES * RSTR * 2);
  float* logits     = (float*)alloc((size_t)7 * LOGSTR * 4);      // slots 0..5=types, 6=pkg
  ushortT* S_all    = (ushortT*)alloc((size_t)7 * SSTR * 2);      // slots 0..5=types, 6=pkg
  float* l2r2       = (float*)alloc((size_t)12 * 32768 * 4);      // l2[6], then r2[6]
  float* ent_slots  = red_buf;
  float* loss_acc   = red_buf + 256;
  float* l2_all = l2r2;
  float* r2_all = l2r2 + (size_t)6 * 32768;

  dim3 blk(256);

  // 1. zero all atomic targets in one pass + zero pad rows of S_t / h_t
  zero_f32<<<dim3(512), blk, 0, stream>>>(p_buf, zero_n);
  zero_tails<<<dim3(30, NTYPES), blk, 0, stream>>>(S_all, h_t_bf);

  // 2-3. input conversions
  convert_pad<<<dim3((NPKG * (KP_IN / 4) + 255) / 256, 1), blk, 0, stream>>>(
      x_pkg, x_pkg_bf, NPKG, INDIM, KP_IN, 0, 0);
  convert_pad<<<dim3((NTGT * (KP_IN / 4) + 255) / 256, NTYPES), blk, 0, stream>>>(
      x_tgt, x_t_bf, NTGT, INDIM, KP_IN, (long)NTGT * INDIM, (long)XSTR);

  // 4-5. weight transposes
  wtrans13<<<dim3((256 * KP_IN + 255) / 256, 13), blk, 0, stream>>>(W1s, Wpkg, W1t, WT_all);
  wtransAss<<<dim3((128 * 256 + 255) / 256, 7), blk, 0, stream>>>(Wassign, WassT);

  // 6-8. CSR (srcs = source ids in CSR order)
  hist_kernel<<<dim3(391, NTYPES), blk, 0, stream>>>(tgt_idx, counts, NEDGE, NTGT);
  scan_kernel<<<dim3(NTYPES), dim3(1024), 0, stream>>>(counts, offs, cursor, NTGT);
  scatter_kernel<<<dim3(391, NTYPES), blk, 0, stream>>>(tgt_idx, src_idx, cursor, srcs, NEDGE, NTGT);

  // 9. l-gemms (z=0..5) + h_pkg gemm (z=6), all A=x_pkg
  {
    MfmaBatch d{};
    for (int z = 0; z < 6; ++z) {
      d.A[z] = x_pkg_bf; d.BT[z] = WT_all + (size_t)z * WSTR;
      d.C[z] = l_bf + (size_t)z * LSTR; d.M[z] = NPKG; d.relu[z] = 0;
    }
    d.A[6] = x_pkg_bf; d.BT[6] = WT_all + (size_t)6 * WSTR;
    d.C[6] = h_pkg_bf; d.M[6] = NPKG; d.relu[6] = 1;
    d.A[7] = d.A[0]; d.BT[7] = d.BT[0]; d.C[7] = d.C[0]; d.M[7] = 0; d.relu[7] = 0;
    gemm_mfma_b<false><<<dim3(2, 157, 7), blk, 0, stream>>>(d, KP_IN, 256);
  }

  // 10. r-gemms (z=0..5)
  {
    MfmaBatch d{};
    for (int z = 0; z < 6; ++z) {
      d.A[z] = x_t_bf + (size_t)z * XSTR; d.BT[z] = WT_all + (size_t)(7 + z) * WSTR;
      d.C[z] = r_bf + (size_t)z * RSTR; d.M[z] = NTGT; d.relu[z] = 0;
    }
    for (int z = 6; z < 8; ++z) { d.A[z] = d.A[0]; d.BT[z] = d.BT[0]; d.C[z] = d.C[0]; d.M[z] = 0; d.relu[z] = 0; }
    gemm_mfma_b<false><<<dim3(2, 235, 6), blk, 0, stream>>>(d, KP_IN, 256);
  }

  // 11. conv1 (all types)
  conv1_agg<<<dim3(7500, NTYPES), blk, 0, stream>>>(l_bf, r_bf, a1, srcs, offs, h_t_bf);

  // 12. assignment logits (z=0..5 types, z=6 pkg)
  {
    MfmaBatch d{};
    for (int z = 0; z < 6; ++z) {
      d.A[z] = h_t_bf + (size_t)z * RSTR; d.BT[z] = WassT + (size_t)(z + 1) * 128 * 256;
      d.C[z] = logits + (size_t)z * LOGSTR; d.M[z] = NTGT; d.relu[z] = 0;
    }
    d.A[6] = h_pkg_bf; d.BT[6] = WassT; d.C[6] = logits + (size_t)6 * LOGSTR;
    d.M[6] = NPKG; d.relu[6] = 0;
    d.A[7] = d.A[0]; d.BT[7] = d.BT[0]; d.C[7] = d.C[0]; d.M[7] = 0; d.relu[7] = 0;
    gemm_mfma_b<true><<<dim3(1, 235, 7), blk, 0, stream>>>(d, 256, 128);
  }

  // 13. softmax + entropy (z=0..6), 32 rows/block
  softmax_ent<<<dim3(938, 7), blk, 0, stream>>>(logits, S_all, ent_slots);

  // 14. pooled features P = S^T h (mats 0..5 types, 6 pkg) — MFMA TN
  {
    TnBatch d{};
    for (int m = 0; m < 6; ++m) {
      d.A[m] = S_all + (size_t)m * SSTR; d.B[m] = h_t_bf + (size_t)m * RSTR;
      d.C[m] = p_buf + (size_t)(m + 1) * 32768;
      d.rA[m] = nullptr; d.rB[m] = nullptr; d.N[m] = MP_TGT;  // pad rows are zeroed
    }
    d.A[6] = S_all + (size_t)6 * SSTR; d.B[6] = h_pkg_bf; d.C[6] = p_buf;
    d.rA[6] = nullptr; d.rB[6] = nullptr; d.N[6] = NPKG;
    d.A[7] = d.A[0]; d.B[7] = d.B[0]; d.C[7] = d.C[0]; d.rA[7] = nullptr; d.rB[7] = nullptr; d.N[7] = 0;
    gemm_tn_mfma<256><<<dim3(2, 1, 7 * 30), blk, 0, stream>>>(d, 1024, 30);
  }

  // 15. M = S^T S (mats 0..5 types, 6 pkg) — MFMA TN
  {
    TnBatch d{};
    for (int m = 0; m < 7; ++m) {
      const ushortT* S = S_all + (size_t)m * SSTR;
      d.A[m] = S; d.B[m] = S; d.C[m] = M_all + (size_t)m * 16384;
      d.rA[m] = nullptr; d.rB[m] = nullptr; d.N[m] = (m == 6) ? NPKG : MP_TGT;
    }
    d.A[7] = d.A[0]; d.B[7] = d.B[0]; d.C[7] = d.C[0]; d.rA[7] = nullptr; d.rB[7] = nullptr; d.N[7] = 0;
    gemm_tn_mfma<128><<<dim3(1, 1, 7 * 30), blk, 0, stream>>>(d, 1024, 30);
  }

  // 16. Apool = gathered S_pkg^T S_t over edges (mats 0..5) — MFMA TN + gather
  {
    TnBatch d{};
    for (int m = 0; m < 6; ++m) {
      d.A[m] = S_all + (size_t)6 * SSTR; d.B[m] = S_all + (size_t)m * SSTR;
      d.C[m] = Apool + (size_t)m * 16384;
      d.rA[m] = src_idx + (long)m * NEDGE; d.rB[m] = tgt_idx + (long)m * NEDGE;
      d.N[m] = NEDGE;
    }
    for (int m = 6; m < 8; ++m) { d.A[m] = d.A[0]; d.B[m] = d.B[0]; d.C[m] = d.C[0]; d.rA[m] = nullptr; d.rB[m] = nullptr; d.N[m] = 0; }
    gemm_tn_mfma<128><<<dim3(1, 1, 6 * 98), blk, 0, stream>>>(d, 1024, 98);
  }

  // 17. link losses
  link_kernel<<<dim3(6), blk, 0, stream>>>(Apool, M_all, (float)NEDGE,
                                           1.f / ((float)NPKG * (float)NTGT), loss_acc);

  // 18-19. conv2
  conv2_gemm<<<dim3(2, 1, 12), blk, 0, stream>>>(p_buf, W2s, W2t, l2r2);
  conv2_attn<<<dim3(128, NTYPES), blk, 0, stream>>>(l2_all, r2_all, Apool, a2, out + 897);

  // 20-21. classifier + loss
  classifier<<<dim3(224), blk, 0, stream>>>(p_buf, Wcls, bcls, out, 896);
  finalize_loss<<<dim3(1), blk, 0, stream>>>(red_buf, out + 896);
}